// Round 3
// 239.801 us; speedup vs baseline: 1.0058x; 1.0058x over previous
//
#include <hip/hip_runtime.h>
#include <hip/hip_bf16.h>
#include <stdint.h>

typedef __hip_bfloat16 bf16;
typedef __attribute__((ext_vector_type(8))) short short8;
typedef __attribute__((ext_vector_type(4))) short short4v;
typedef __attribute__((ext_vector_type(4))) float float4v;

static constexpr int nB = 2, nS = 2048, nD = 1024, nH = 16, nHD = 64;
static constexpr int nBS = nB * nS;   // 4096

#define AS_GLOBAL __attribute__((address_space(1)))
#define AS_LDS    __attribute__((address_space(3)))

union Frag16B { short8 v; uint4 u4; uint2 u2[2]; };

__device__ __forceinline__ void gload_lds16(const void* g, void* l) {
  __builtin_amdgcn_global_load_lds((AS_GLOBAL uint32_t*)(g), (AS_LDS uint32_t*)(l), 16, 0, 0);
}

__device__ __forceinline__ float fast_exp2(float x) {
#if __has_builtin(__builtin_amdgcn_exp2f)
  return __builtin_amdgcn_exp2f(x);
#else
  float r; asm volatile("v_exp_f32 %0, %1" : "=v"(r) : "v"(x)); return r;
#endif
}

// drain LDS ops but NOT vmem: prefetch global loads stay in flight across the barrier
__device__ __forceinline__ void lds_barrier() {
  asm volatile("s_waitcnt lgkmcnt(0)\ns_barrier" ::: "memory");
}

__device__ __forceinline__ void lgkm_wait() {
  asm volatile("s_waitcnt lgkmcnt(0)" ::: "memory");
}

// ---------------------------------------------------------------- prep: cast QKV->bf16, W->W^T bf16, rope tables
__global__ __launch_bounds__(256) void prep_kernel(
    const float* __restrict__ Qin, const float* __restrict__ Kin, const float* __restrict__ Vin,
    const float* __restrict__ Wq, const float* __restrict__ Wk,
    const float* __restrict__ Wv, const float* __restrict__ Wo,
    bf16* __restrict__ Qbf, bf16* __restrict__ Kbf, bf16* __restrict__ Vbf,
    bf16* __restrict__ WqT, bf16* __restrict__ WkT, bf16* __restrict__ WvT, bf16* __restrict__ WoT,
    bf16* __restrict__ cos_t, bf16* __restrict__ sin_t) {
  __shared__ float tile[64][65];
  int bx = blockIdx.x, t = threadIdx.x;
  if (bx < 3072) {
    int tz = bx >> 10, blk = bx & 1023;
    const float* src = tz == 0 ? Qin : tz == 1 ? Kin : Vin;
    bf16* dst = tz == 0 ? Qbf : tz == 1 ? Kbf : Vbf;
#pragma unroll
    for (int i = 0; i < 4; ++i) {
      int idx = blk * 1024 + i * 256 + t;  // float4 index
      float4 v = ((const float4*)src)[idx];
      union { bf16 b[4]; uint2 u; } tmp;
      tmp.b[0] = __float2bfloat16(v.x);
      tmp.b[1] = __float2bfloat16(v.y);
      tmp.b[2] = __float2bfloat16(v.z);
      tmp.b[3] = __float2bfloat16(v.w);
      ((uint2*)dst)[idx] = tmp.u;
    }
  } else if (bx < 4096) {
    int idx = bx - 3072;
    int z = idx >> 8;
    const float* W = z == 0 ? Wq : z == 1 ? Wk : z == 2 ? Wv : Wo;
    bf16* T = z == 0 ? WqT : z == 1 ? WkT : z == 2 ? WvT : WoT;
    int tk = (idx & 15) * 64, tn = ((idx >> 4) & 15) * 64;
    int c = t & 63, r0 = t >> 6;
#pragma unroll
    for (int i = 0; i < 16; ++i) {
      int r = i * 4 + r0;
      tile[r][c] = W[(size_t)(tk + r) * nD + tn + c];
    }
    __syncthreads();
#pragma unroll
    for (int i = 0; i < 16; ++i) {
      int r = i * 4 + r0;
      T[(size_t)(tn + r) * nD + tk + c] = __float2bfloat16(tile[c][r]);
    }
  } else {
    int base = (bx - 4096) * 1024 + t * 4;
#pragma unroll
    for (int i = 0; i < 4; ++i) {
      int e = base + i;
      int s = e >> 5, j = e & 31;
      float inv_freq = powf(100000.0f, -(float)(2 * j) / 64.0f);
      float g = (float)s * inv_freq;
      cos_t[e] = __float2bfloat16(cosf(g));
      sin_t[e] = __float2bfloat16(sinf(g));
    }
  }
}

// ---------------------------------------------------------------- fused projection GEMM, 256x256 tile, BK=32,
// 8 waves (2Mx4N), double-buffered 64 KiB LDS, 3-phase interleave with counted vmcnt.
// LDS layout: paired rows — LDS row R (128 B, 8 chunks of 16 B) holds global rows {2R, 2R+1} x 32 k;
// chunk c_orig = (m&1)*4 + kchunk, stored at c_orig ^ (R&7)  (2-way bank conflict = free).
// Per K-step T (cu = T&1):
//   p0: stage B(T+1)->buf^1 | 8 ds_read (A lower + B) | 16 MFMA | bar
//   p1: 4 ds_read (A upper) | lgkmcnt(0)              |  8 MFMA | bar   (all waves drained cu)
//   p2: stage A(T+2)->cu (safe after p1 bar)          |  8 MFMA | vmcnt(2) | bar
// vmcnt(2) leaves only A(T+2) in flight; A(T+1)/B(T+1) land with ~2 K-steps of flight time.
__global__ __launch_bounds__(512, 2) void gemm_qkv_kernel(
    const bf16* __restrict__ A0, const bf16* __restrict__ A1, const bf16* __restrict__ A2,
    const bf16* __restrict__ Bt0, const bf16* __restrict__ Bt1, const bf16* __restrict__ Bt2,
    bf16* __restrict__ q_h, bf16* __restrict__ k_h, bf16* __restrict__ vt_h,
    const bf16* __restrict__ cos_t, const bf16* __restrict__ sin_t) {
  const int z = blockIdx.z;
  const bf16* __restrict__ A  = z == 0 ? A0 : (z == 1 ? A1 : A2);
  const bf16* __restrict__ Bt = z == 0 ? Bt0 : (z == 1 ? Bt1 : Bt2);

  __shared__ bf16 As[2 * 256 * 32];   // 32 KiB (two 16 KiB buffers)
  __shared__ bf16 Bs[2 * 256 * 32];   // 32 KiB

  const int t = threadIdx.x;          // 0..511
  const int lane = t & 63;
  const int wid = t >> 6;             // 0..7
  const int quad = lane >> 4;
  const int l16 = lane & 15;
  const int wm = wid >> 2;            // 0..1 -> 128 rows each
  const int wn = wid & 3;             // 0..3 -> 64 cols each (one head per wave)
  const int m0 = blockIdx.x * 256;    // 16 m-tiles
  const int n0 = blockIdx.y * 256;    // 4 n-tiles

  // staging constants: linear LDS dest (wave-uniform base + lane*16B), pre-swizzled global source
  const int sc    = (t & 7) ^ ((t >> 3) & 7);   // c_orig for this lane's 16B chunk
  const int sml   = 2 * (t >> 3) + (sc >> 2);   // m row within 128-row half
  const int skoff = (sc & 3) * 8;               // k element offset
  const int swave = wid * 512;                  // wave-uniform LDS elem base within half

  // fragment-read constants
  const int R0a = wm * 64 + (l16 >> 1);
  const int R0b = wn * 32 + (l16 >> 1);
  const int cpar = (l16 & 1) * 4;
  const int abase = R0a * 64 + (((cpar + quad) ^ (R0a & 7)) * 8);  // + mi*512 (+buf)
  const int bbase = R0b * 64 + (((cpar + quad) ^ (R0b & 7)) * 8);  // + ni*512 (+buf)

#define STAGE_A(KT, BUF) do { \
    const bf16* ag_ = A + (size_t)(m0 + sml) * nD + (KT) * 32 + skoff; \
    gload_lds16(ag_, As + (BUF) + swave); \
    gload_lds16(ag_ + (size_t)128 * nD, As + (BUF) + 4096 + swave); \
  } while (0)
#define STAGE_B(KT, BUF) do { \
    const bf16* bg_ = Bt + (size_t)(n0 + sml) * nD + (KT) * 32 + skoff; \
    gload_lds16(bg_, Bs + (BUF) + swave); \
    gload_lds16(bg_ + (size_t)128 * nD, Bs + (BUF) + 4096 + swave); \
  } while (0)

  float4v acc[8][4] = {};

  // prologue: A(0),B(0) -> buf0; A(1) -> buf1; vmcnt(2) leaves A(1) in flight
  STAGE_A(0, 0);
  STAGE_B(0, 0);
  STAGE_A(1, 8192);
  asm volatile("s_waitcnt vmcnt(2)" ::: "memory");
  __builtin_amdgcn_s_barrier();

#pragma unroll 2
  for (int T = 0; T < 32; ++T) {
    const int cu = (T & 1) * 8192;
    const int nx = cu ^ 8192;

    // ---- phase 0
    if (T < 31) STAGE_B(T + 1, nx);
    Frag16B fa[4], fb[4];
#pragma unroll
    for (int mi = 0; mi < 4; ++mi) fa[mi].u4 = *(const uint4*)&As[cu + abase + mi * 512];
#pragma unroll
    for (int ni = 0; ni < 4; ++ni) fb[ni].u4 = *(const uint4*)&Bs[cu + bbase + ni * 512];
    __builtin_amdgcn_s_setprio(1);
#pragma unroll
    for (int mi = 0; mi < 4; ++mi)
#pragma unroll
      for (int ni = 0; ni < 4; ++ni)
        acc[mi][ni] = __builtin_amdgcn_mfma_f32_16x16x32_bf16(fa[mi].v, fb[ni].v, acc[mi][ni], 0, 0, 0);
    __builtin_amdgcn_s_setprio(0);
    __builtin_amdgcn_s_barrier();

    // ---- phase 1: last reads of cu; drain; barrier => every wave done reading cu
    Frag16B fa2[4];
#pragma unroll
    for (int mi = 0; mi < 4; ++mi) fa2[mi].u4 = *(const uint4*)&As[cu + abase + (mi + 4) * 512];
    asm volatile("s_waitcnt lgkmcnt(0)" ::: "memory");
    __builtin_amdgcn_s_setprio(1);
#pragma unroll
    for (int mi = 0; mi < 2; ++mi)
#pragma unroll
      for (int ni = 0; ni < 4; ++ni)
        acc[4 + mi][ni] = __builtin_amdgcn_mfma_f32_16x16x32_bf16(fa2[mi].v, fb[ni].v, acc[4 + mi][ni], 0, 0, 0);
    __builtin_amdgcn_s_setprio(0);
    __builtin_amdgcn_s_barrier();

    // ---- phase 2: stage A(T+2) into cu (drained); counted vmcnt
    if (T < 30) STAGE_A(T + 2, cu);
    __builtin_amdgcn_s_setprio(1);
#pragma unroll
    for (int mi = 2; mi < 4; ++mi)
#pragma unroll
      for (int ni = 0; ni < 4; ++ni)
        acc[4 + mi][ni] = __builtin_amdgcn_mfma_f32_16x16x32_bf16(fa2[mi].v, fb[ni].v, acc[4 + mi][ni], 0, 0, 0);
    __builtin_amdgcn_s_setprio(0);
    if (T < 30) { asm volatile("s_waitcnt vmcnt(2)" ::: "memory"); }
    else        { asm volatile("s_waitcnt vmcnt(0)" ::: "memory"); }
    __builtin_amdgcn_s_barrier();
  }
#undef STAGE_A
#undef STAGE_B

  // ---- epilogue: RoPE + RMSNorm (q,k) or transposed store (v)
  const int col0 = n0 + wn * 64;   // multiple of 64 -> one head per wave
  if (z <= 1) {
    bf16* dst = z ? k_h : q_h;
#pragma unroll
    for (int mi = 0; mi < 8; ++mi)
#pragma unroll
      for (int r = 0; r < 4; ++r) {
        int row = m0 + wm * 128 + mi * 16 + quad * 4 + r;
        int s = row & (nS - 1);
        float x0 = acc[mi][0][r], x1 = acc[mi][1][r], x2 = acc[mi][2][r], x3 = acc[mi][3][r];
        float y[4];
#pragma unroll
        for (int p = 0; p < 2; ++p) {
          int d = p * 16 + l16;
          float c = __bfloat162float(cos_t[s * 32 + d]);
          float sn = __bfloat162float(sin_t[s * 32 + d]);
          float xa = p ? x1 : x0, xb = p ? x3 : x2;
          y[p] = xa * c + xb * sn;
          y[p + 2] = xb * c - xa * sn;
        }
        float ss = y[0] * y[0] + y[1] * y[1] + y[2] * y[2] + y[3] * y[3];
#pragma unroll
        for (int m = 1; m <= 8; m <<= 1) ss += __shfl_xor(ss, m, 64);
        float inv = 1.0f / sqrtf(ss * (1.0f / 64.0f) + 1e-9f);
#pragma unroll
        for (int ni = 0; ni < 4; ++ni)
          dst[(size_t)row * nD + col0 + ni * 16 + l16] = __float2bfloat16(y[ni] * inv);
      }
  } else {
    // V: write transposed -> vt_h [b][h][d][s]
#pragma unroll
    for (int mi = 0; mi < 8; ++mi)
#pragma unroll
      for (int r = 0; r < 4; ++r) {
        int row = m0 + wm * 128 + mi * 16 + quad * 4 + r;
        int b = row >> 11, s = row & (nS - 1);
#pragma unroll
        for (int ni = 0; ni < 4; ++ni) {
          int col = col0 + ni * 16 + l16;
          int h = col >> 6, d = col & 63;
          vt_h[((size_t)((b * nH + h) * 64 + d)) * nS + s] = __float2bfloat16(acc[mi][ni][r]);
        }
      }
  }
}

// ---------------------------------------------------------------- output GEMM: 64x128 tile, BK=64, grid (64, 8)
__global__ __launch_bounds__(256) void gemm_out_kernel(
    const bf16* __restrict__ A, const bf16* __restrict__ Bt, float* __restrict__ C) {
  __shared__ bf16 As[64 * 64];
  __shared__ bf16 Bs[128 * 64];
  const int t = threadIdx.x;
  const int lane = t & 63;
  const int wid = t >> 6;
  const int quad = lane >> 4;
  const int l16 = lane & 15;
  const int wm = wid >> 1;
  const int wn = wid & 1;
  const int m0 = blockIdx.x * 64;
  const int n0 = blockIdx.y * 128;
  const int K = nD;
  const int rloc = lane >> 3, cl = lane & 7;
  const int cg = cl ^ rloc;

  float4v acc[2][4] = {};
  for (int kt = 0; kt < K; kt += 64) {
    __syncthreads();
#pragma unroll
    for (int p = 0; p < 2; ++p) {
      int rowbase = (p * 4 + wid) * 8;
      gload_lds16(A + (size_t)(m0 + rowbase + rloc) * K + kt + cg * 8, As + (size_t)rowbase * 64);
    }
#pragma unroll
    for (int p = 0; p < 4; ++p) {
      int rowbase = (p * 4 + wid) * 8;
      gload_lds16(Bt + (size_t)(n0 + rowbase + rloc) * K + kt + cg * 8, Bs + (size_t)rowbase * 64);
    }
    __syncthreads();

#pragma unroll
    for (int ks = 0; ks < 2; ++ks) {
      Frag16B a[2], b[4];
#pragma unroll
      for (int mi = 0; mi < 2; ++mi) {
        int row = wm * 32 + mi * 16 + l16;
        int ch = (ks * 4 + quad) ^ (row & 7);
        a[mi].u4 = *(const uint4*)&As[row * 64 + ch * 8];
      }
#pragma unroll
      for (int ni = 0; ni < 4; ++ni) {
        int row = wn * 64 + ni * 16 + l16;
        int ch = (ks * 4 + quad) ^ (row & 7);
        b[ni].u4 = *(const uint4*)&Bs[row * 64 + ch * 8];
      }
#pragma unroll
      for (int mi = 0; mi < 2; ++mi)
#pragma unroll
        for (int ni = 0; ni < 4; ++ni)
          acc[mi][ni] = __builtin_amdgcn_mfma_f32_16x16x32_bf16(a[mi].v, b[ni].v, acc[mi][ni], 0, 0, 0);
    }
  }
#pragma unroll
  for (int mi = 0; mi < 2; ++mi)
#pragma unroll
    for (int ni = 0; ni < 4; ++ni)
#pragma unroll
      for (int r = 0; r < 4; ++r) {
        int row = m0 + wm * 32 + mi * 16 + quad * 4 + r;
        int col = n0 + wn * 64 + ni * 16 + l16;
        C[(size_t)row * nD + col] = acc[mi][ni][r];
      }
}

// ---------------------------------------------------------------- flash attention v6: one 128-q tile per block,
// grid 512 = 2 blocks/CU (long+short causal tiles of the SAME head co-resident per CU),
// XCD-pinned bh, LDS-staged K/V double-buffered w/ vmem prefetch across lgkm-only barrier,
// register-resident P, LDS-transpose epilogue.
static constexpr float SC = 0.18033688011112042f;  // 0.125 * log2(e)

__global__ __launch_bounds__(256, 2) void attn_kernel(const bf16* __restrict__ q_h,
                                                      const bf16* __restrict__ k_h,
                                                      const bf16* __restrict__ vt_h,
                                                      bf16* __restrict__ vals) {
  __shared__ bf16 lds_buf[4 * 4096];   // [ K0 | K1 | V0 | V1 ]; front 4608 reused as epilogue scratch

  const int t = threadIdx.x;
  const int lane = t & 63, wid = t >> 6, quad = lane >> 4, l16 = lane & 15;
  const int id = blockIdx.x;           // 0..511
  const int xcd = id & 7;              // round-robin XCD heuristic (validated r5: FETCH 101->13MB)
  const int j = id >> 3;               // 0..63 per-XCD index
  const int jj = j & 31;
  const int bh = xcd * 4 + (jj & 3);   // 4 heads per XCD; pair blocks share bh
  const int u = jj >> 2;               // 0..7
  const int qt = (j < 32) ? (15 - u) : u;   // first CU-slot: long tiles; second: complementary short
  const int b = bh >> 4, h = bh & 15;

  const bf16* Kbase = k_h + ((size_t)b * nS) * nD + h * 64;
  const bf16* Vbase = vt_h + (size_t)bh * 64 * nS;  // [d][s]

  const int row0 = t >> 3;         // 0..31
  const int cl = t & 7;
  const int cg = cl ^ (row0 & 7);  // global chunk fetched into LDS chunk cl
  const int r7 = l16 & 7;

  bf16* const scratch = lds_buf + wid * 1152;  // 16 x 72 per wave per qs round

  const int nkt = 2 * qt + 2;
  const int q0w = qt * 128 + wid * 32;         // wave's first q row

  // Q B-frags (n=q=l16, k=d=quad*8+j), 2 q-slices x 2 d-halves
  Frag16B qf[2][2];
#pragma unroll
  for (int qs = 0; qs < 2; ++qs) {
    const bf16* qp = q_h + ((size_t)(b * nS + q0w + qs * 16 + l16)) * nD + h * 64;
    qf[qs][0].u4 = *(const uint4*)(qp + quad * 8);
    qf[qs][1].u4 = *(const uint4*)(qp + 32 + quad * 8);
  }

  // prologue: load tile 0 into regs
  uint4 kreg[2], vreg[2];
#pragma unroll
  for (int i = 0; i < 2; ++i) {
    kreg[i] = *(const uint4*)(Kbase + (size_t)(row0 + i * 32) * nD + cg * 8);
    vreg[i] = *(const uint4*)(Vbase + (size_t)(row0 + i * 32) * nS + cg * 8);
  }

  float4v o_acc[2][4] = {};
  float l_acc[2] = {0.f, 0.f};

  for (int kt = 0; kt < nkt; ++kt) {
    bf16* Kb = lds_buf + (kt & 1) * 4096;
    bf16* Vb = lds_buf + 8192 + (kt & 1) * 4096;
    // staged regs -> LDS (contiguous per wave, conflict-free)
#pragma unroll
    for (int i = 0; i < 2; ++i) {
      *(uint4*)&Kb[(row0 + i * 32) * 64 + cl * 8] = kreg[i];
      *(uint4*)&Vb[(row0 + i * 32) * 64 + cl * 8] = vreg[i];
    }
    // prefetch next tile (global loads stay in flight across the barrier)
    if (kt + 1 < nkt) {
#pragma unroll
      for (int i = 0; i < 2; ++i) {
        kreg[i] = *(const uint4*)(Kbase + (size_t)((kt + 1) * 64 + row0 + i * 32) * nD + cg * 8);
        vreg[i] = *(const uint4*)(Vbase + (size_t)(row0 + i * 32) * nS + (kt + 1) * 64 + cg * 8);
      }
    }
    lds_barrier();

    if (kt * 64 <= q0w + 31) {   // wave has unmasked keys in this tile
      // S^T[key][q] for both q-slices; K frags shared
      float4v st[2][4];
#pragma unroll
      for (int kt4 = 0; kt4 < 4; ++kt4) {
        int row = kt4 * 16 + l16;
        Frag16B k0, k1;
        k0.u4 = *(const uint4*)&Kb[row * 64 + ((quad ^ r7) * 8)];
        k1.u4 = *(const uint4*)&Kb[row * 64 + (((quad + 4) ^ r7) * 8)];
#pragma unroll
        for (int qs = 0; qs < 2; ++qs) {
          float4v zz = {};
          zz = __builtin_amdgcn_mfma_f32_16x16x32_bf16(k0.v, qf[qs][0].v, zz, 0, 0, 0);
          st[qs][kt4] = __builtin_amdgcn_mfma_f32_16x16x32_bf16(k1.v, qf[qs][1].v, zz, 0, 0, 0);
        }
      }

      // exp + pack P^T B-frags (k=key=quad*4+r == C-layout row)
      short4v pf[2][4];
      const bool need_mask = (kt * 64 + 63) > q0w;   // wave-uniform
      if (need_mask) {
#pragma unroll
        for (int qs = 0; qs < 2; ++qs) {
          int qg = q0w + qs * 16 + l16;
#pragma unroll
          for (int kt4 = 0; kt4 < 4; ++kt4) {
            int key0 = kt * 64 + kt4 * 16 + quad * 4;
#pragma unroll
            for (int r = 0; r < 4; ++r) {
              float x = st[qs][kt4][r] * SC;
              if (key0 + r > qg) x = -12000.0f;
              float p = fast_exp2(x);
              l_acc[qs] += p;
              union { bf16 hh; short ss; } cv;
              cv.hh = __float2bfloat16(p);
              pf[qs][kt4][r] = cv.ss;
            }
          }
        }
      } else {
#pragma unroll
        for (int qs = 0; qs < 2; ++qs)
#pragma unroll
          for (int kt4 = 0; kt4 < 4; ++kt4)
#pragma unroll
            for (int r = 0; r < 4; ++r) {
              float p = fast_exp2(st[qs][kt4][r] * SC);
              l_acc[qs] += p;
              union { bf16 hh; short ss; } cv;
              cv.hh = __float2bfloat16(p);
              pf[qs][kt4][r] = cv.ss;
            }
      }

      // O^T[d][q] += V^T·P^T ; V frags shared across q-slices
#pragma unroll
      for (int dt = 0; dt < 4; ++dt) {
        int row = dt * 16 + l16;
#pragma unroll
        for (int kt4 = 0; kt4 < 4; ++kt4) {
          int chunk = kt4 * 2 + (quad >> 1);
          union { uint2 u; short4v s; } vv;
          vv.u = *(const uint2*)&Vb[row * 64 + ((chunk ^ r7) * 8) + (quad & 1) * 4];
          o_acc[0][dt] = __builtin_amdgcn_mfma_f32_16x16x16bf16_1k(vv.s, pf[0][kt4], o_acc[0][dt], 0, 0, 0);
          o_acc[1][dt] = __builtin_amdgcn_mfma_f32_16x16x16bf16_1k(vv.s, pf[1][kt4], o_acc[1][dt], 0, 0, 0);
        }
      }
    }
  }

  // ---- epilogue: row-sum reduce, LDS-transpose, coalesced 16B stores
  lds_barrier();  // all waves done reading K/V before scratch overwrites them
#pragma unroll
  for (int qs = 0; qs < 2; ++qs) {
    float la = l_acc[qs];
    la += __shfl_xor(la, 16, 64);
    la += __shfl_xor(la, 32, 64);
    float inv_l = 1.0f / la;
    // write transposed: scratch[q_loc=l16][d]
#pragma unroll
    for (int dt = 0; dt < 4; ++dt) {
      union { bf16 b2[2]; uint u; } p01, p23;
      p01.b2[0] = __float2bfloat16(o_acc[qs][dt][0] * inv_l);
      p01.b2[1] = __float2bfloat16(o_acc[qs][dt][1] * inv_l);
      p23.b2[0] = __float2bfloat16(o_acc[qs][dt][2] * inv_l);
      p23.b2[1] = __float2bfloat16(o_acc[qs][dt][3] * inv_l);
      *(uint*)&scratch[l16 * 72 + dt * 16 + quad * 4] = p01.u;
      *(uint*)&scratch[l16 * 72 + dt * 16 + quad * 4 + 2] = p23.u;
    }
    lgkm_wait();  // own writes visible to own reads
    uint4 r0 = *(const uint4*)&scratch[l16 * 72 + quad * 16];
    uint4 r1 = *(const uint4*)&scratch[l16 * 72 + quad * 16 + 8];
    int qrow = q0w + qs * 16 + l16;
    bf16* vp = vals + ((size_t)(b * nS + qrow)) * nD + h * 64 + quad * 16;
    *(uint4*)(vp) = r0;
    *(uint4*)(vp + 8) = r1;
    lgkm_wait();  // reads done before next qs overwrites region
  }
}

// ---------------------------------------------------------------- launch
extern "C" void kernel_launch(void* const* d_in, const int* in_sizes, int n_in,
                              void* d_out, int out_size, void* d_ws, size_t ws_size,
                              hipStream_t stream) {
  const float* Qin = (const float*)d_in[0];
  const float* Kin = (const float*)d_in[1];
  const float* Vin = (const float*)d_in[2];
  const float* Wq = (const float*)d_in[4];
  const float* Wk = (const float*)d_in[5];
  const float* Wv = (const float*)d_in[6];
  const float* Wo = (const float*)d_in[7];
  float* out = (float*)d_out;

  char* ws = (char*)d_ws;
  const size_t MB = 1u << 20;
  bf16* Qbf = (bf16*)(ws + 0 * MB);
  bf16* Kbf = (bf16*)(ws + 8 * MB);
  bf16* Vbf = (bf16*)(ws + 16 * MB);
  bf16* WqT = (bf16*)(ws + 24 * MB);
  bf16* WkT = (bf16*)(ws + 26 * MB);
  bf16* WvT = (bf16*)(ws + 28 * MB);
  bf16* WoT = (bf16*)(ws + 30 * MB);
  bf16* cos_t = (bf16*)(ws + 32 * MB);
  bf16* sin_t = (bf16*)(ws + 33 * MB);
  bf16* q_h = (bf16*)(ws + 34 * MB);
  bf16* k_h = (bf16*)(ws + 42 * MB);
  bf16* vt_h = (bf16*)(ws + 50 * MB);
  bf16* vals = (bf16*)(ws + 58 * MB);

  prep_kernel<<<4160, 256, 0, stream>>>(Qin, Kin, Vin, Wq, Wk, Wv, Wo,
                                        Qbf, Kbf, Vbf, WqT, WkT, WvT, WoT, cos_t, sin_t);

  gemm_qkv_kernel<<<dim3(16, 4, 3), 512, 0, stream>>>(Qbf, Kbf, Vbf, WqT, WkT, WvT,
                                                      q_h, k_h, vt_h, cos_t, sin_t);

  attn_kernel<<<512, 256, 0, stream>>>(q_h, k_h, vt_h, vals);

  gemm_out_kernel<<<dim3(64, 8), 256, 0, stream>>>(vals, WoT, out);
}

// Round 4
// 223.184 us; speedup vs baseline: 1.0807x; 1.0745x over previous
//
#include <hip/hip_runtime.h>
#include <hip/hip_bf16.h>
#include <stdint.h>

typedef __hip_bfloat16 bf16;
typedef __attribute__((ext_vector_type(8))) short short8;
typedef __attribute__((ext_vector_type(4))) short short4v;
typedef __attribute__((ext_vector_type(4))) float float4v;

static constexpr int nB = 2, nS = 2048, nD = 1024, nH = 16, nHD = 64;
static constexpr int nBS = nB * nS;   // 4096

#define AS_GLOBAL __attribute__((address_space(1)))
#define AS_LDS    __attribute__((address_space(3)))

union Frag16B { short8 v; uint4 u4; uint2 u2[2]; };

__device__ __forceinline__ void gload_lds16(const void* g, void* l) {
  __builtin_amdgcn_global_load_lds((AS_GLOBAL uint32_t*)(g), (AS_LDS uint32_t*)(l), 16, 0, 0);
}

__device__ __forceinline__ float fast_exp2(float x) {
#if __has_builtin(__builtin_amdgcn_exp2f)
  return __builtin_amdgcn_exp2f(x);
#else
  float r; asm volatile("v_exp_f32 %0, %1" : "=v"(r) : "v"(x)); return r;
#endif
}

// drain LDS ops but NOT vmem: prefetch global loads stay in flight across the barrier
__device__ __forceinline__ void lds_barrier() {
  asm volatile("s_waitcnt lgkmcnt(0)\ns_barrier" ::: "memory");
}

__device__ __forceinline__ void lgkm_wait() {
  asm volatile("s_waitcnt lgkmcnt(0)" ::: "memory");
}

// ---------------------------------------------------------------- prep: cast QKV->bf16, W->W^T bf16, rope tables
__global__ __launch_bounds__(256) void prep_kernel(
    const float* __restrict__ Qin, const float* __restrict__ Kin, const float* __restrict__ Vin,
    const float* __restrict__ Wq, const float* __restrict__ Wk,
    const float* __restrict__ Wv, const float* __restrict__ Wo,
    bf16* __restrict__ Qbf, bf16* __restrict__ Kbf, bf16* __restrict__ Vbf,
    bf16* __restrict__ WqT, bf16* __restrict__ WkT, bf16* __restrict__ WvT, bf16* __restrict__ WoT,
    bf16* __restrict__ cos_t, bf16* __restrict__ sin_t) {
  __shared__ float tile[64][65];
  int bx = blockIdx.x, t = threadIdx.x;
  if (bx < 3072) {
    int tz = bx >> 10, blk = bx & 1023;
    const float* src = tz == 0 ? Qin : tz == 1 ? Kin : Vin;
    bf16* dst = tz == 0 ? Qbf : tz == 1 ? Kbf : Vbf;
#pragma unroll
    for (int i = 0; i < 4; ++i) {
      int idx = blk * 1024 + i * 256 + t;  // float4 index
      float4 v = ((const float4*)src)[idx];
      union { bf16 b[4]; uint2 u; } tmp;
      tmp.b[0] = __float2bfloat16(v.x);
      tmp.b[1] = __float2bfloat16(v.y);
      tmp.b[2] = __float2bfloat16(v.z);
      tmp.b[3] = __float2bfloat16(v.w);
      ((uint2*)dst)[idx] = tmp.u;
    }
  } else if (bx < 4096) {
    int idx = bx - 3072;
    int z = idx >> 8;
    const float* W = z == 0 ? Wq : z == 1 ? Wk : z == 2 ? Wv : Wo;
    bf16* T = z == 0 ? WqT : z == 1 ? WkT : z == 2 ? WvT : WoT;
    int tk = (idx & 15) * 64, tn = ((idx >> 4) & 15) * 64;
    int c = t & 63, r0 = t >> 6;
#pragma unroll
    for (int i = 0; i < 16; ++i) {
      int r = i * 4 + r0;
      tile[r][c] = W[(size_t)(tk + r) * nD + tn + c];
    }
    __syncthreads();
#pragma unroll
    for (int i = 0; i < 16; ++i) {
      int r = i * 4 + r0;
      T[(size_t)(tn + r) * nD + tk + c] = __float2bfloat16(tile[c][r]);
    }
  } else {
    int base = (bx - 4096) * 1024 + t * 4;
#pragma unroll
    for (int i = 0; i < 4; ++i) {
      int e = base + i;
      int s = e >> 5, j = e & 31;
      float inv_freq = powf(100000.0f, -(float)(2 * j) / 64.0f);
      float g = (float)s * inv_freq;
      cos_t[e] = __float2bfloat16(cosf(g));
      sin_t[e] = __float2bfloat16(sinf(g));
    }
  }
}

// ---------------------------------------------------------------- fused projection GEMM, 256x256 tile, BK=32,
// 8 waves (2Mx4N), double-buffered 64 KiB LDS, 3-phase interleave with counted vmcnt.
__global__ __launch_bounds__(512, 2) void gemm_qkv_kernel(
    const bf16* __restrict__ A0, const bf16* __restrict__ A1, const bf16* __restrict__ A2,
    const bf16* __restrict__ Bt0, const bf16* __restrict__ Bt1, const bf16* __restrict__ Bt2,
    bf16* __restrict__ q_h, bf16* __restrict__ k_h, bf16* __restrict__ vt_h,
    const bf16* __restrict__ cos_t, const bf16* __restrict__ sin_t) {
  const int z = blockIdx.z;
  const bf16* __restrict__ A  = z == 0 ? A0 : (z == 1 ? A1 : A2);
  const bf16* __restrict__ Bt = z == 0 ? Bt0 : (z == 1 ? Bt1 : Bt2);

  __shared__ bf16 As[2 * 256 * 32];   // 32 KiB (two 16 KiB buffers)
  __shared__ bf16 Bs[2 * 256 * 32];   // 32 KiB

  const int t = threadIdx.x;          // 0..511
  const int lane = t & 63;
  const int wid = t >> 6;             // 0..7
  const int quad = lane >> 4;
  const int l16 = lane & 15;
  const int wm = wid >> 2;            // 0..1 -> 128 rows each
  const int wn = wid & 3;             // 0..3 -> 64 cols each (one head per wave)
  const int m0 = blockIdx.x * 256;    // 16 m-tiles
  const int n0 = blockIdx.y * 256;    // 4 n-tiles

  // staging constants: linear LDS dest (wave-uniform base + lane*16B), pre-swizzled global source
  const int sc    = (t & 7) ^ ((t >> 3) & 7);   // c_orig for this lane's 16B chunk
  const int sml   = 2 * (t >> 3) + (sc >> 2);   // m row within 128-row half
  const int skoff = (sc & 3) * 8;               // k element offset
  const int swave = wid * 512;                  // wave-uniform LDS elem base within half

  // fragment-read constants
  const int R0a = wm * 64 + (l16 >> 1);
  const int R0b = wn * 32 + (l16 >> 1);
  const int cpar = (l16 & 1) * 4;
  const int abase = R0a * 64 + (((cpar + quad) ^ (R0a & 7)) * 8);  // + mi*512 (+buf)
  const int bbase = R0b * 64 + (((cpar + quad) ^ (R0b & 7)) * 8);  // + ni*512 (+buf)

#define STAGE_A(KT, BUF) do { \
    const bf16* ag_ = A + (size_t)(m0 + sml) * nD + (KT) * 32 + skoff; \
    gload_lds16(ag_, As + (BUF) + swave); \
    gload_lds16(ag_ + (size_t)128 * nD, As + (BUF) + 4096 + swave); \
  } while (0)
#define STAGE_B(KT, BUF) do { \
    const bf16* bg_ = Bt + (size_t)(n0 + sml) * nD + (KT) * 32 + skoff; \
    gload_lds16(bg_, Bs + (BUF) + swave); \
    gload_lds16(bg_ + (size_t)128 * nD, Bs + (BUF) + 4096 + swave); \
  } while (0)

  float4v acc[8][4] = {};

  // prologue: A(0),B(0) -> buf0; A(1) -> buf1; vmcnt(2) leaves A(1) in flight
  STAGE_A(0, 0);
  STAGE_B(0, 0);
  STAGE_A(1, 8192);
  asm volatile("s_waitcnt vmcnt(2)" ::: "memory");
  __builtin_amdgcn_s_barrier();

#pragma unroll 2
  for (int T = 0; T < 32; ++T) {
    const int cu = (T & 1) * 8192;
    const int nx = cu ^ 8192;

    // ---- phase 0
    if (T < 31) STAGE_B(T + 1, nx);
    Frag16B fa[4], fb[4];
#pragma unroll
    for (int mi = 0; mi < 4; ++mi) fa[mi].u4 = *(const uint4*)&As[cu + abase + mi * 512];
#pragma unroll
    for (int ni = 0; ni < 4; ++ni) fb[ni].u4 = *(const uint4*)&Bs[cu + bbase + ni * 512];
    __builtin_amdgcn_s_setprio(1);
#pragma unroll
    for (int mi = 0; mi < 4; ++mi)
#pragma unroll
      for (int ni = 0; ni < 4; ++ni)
        acc[mi][ni] = __builtin_amdgcn_mfma_f32_16x16x32_bf16(fa[mi].v, fb[ni].v, acc[mi][ni], 0, 0, 0);
    __builtin_amdgcn_s_setprio(0);
    __builtin_amdgcn_s_barrier();

    // ---- phase 1: last reads of cu; drain; barrier => every wave done reading cu
    Frag16B fa2[4];
#pragma unroll
    for (int mi = 0; mi < 4; ++mi) fa2[mi].u4 = *(const uint4*)&As[cu + abase + (mi + 4) * 512];
    asm volatile("s_waitcnt lgkmcnt(0)" ::: "memory");
    __builtin_amdgcn_s_setprio(1);
#pragma unroll
    for (int mi = 0; mi < 2; ++mi)
#pragma unroll
      for (int ni = 0; ni < 4; ++ni)
        acc[4 + mi][ni] = __builtin_amdgcn_mfma_f32_16x16x32_bf16(fa2[mi].v, fb[ni].v, acc[4 + mi][ni], 0, 0, 0);
    __builtin_amdgcn_s_setprio(0);
    __builtin_amdgcn_s_barrier();

    // ---- phase 2: stage A(T+2) into cu (drained); counted vmcnt
    if (T < 30) STAGE_A(T + 2, cu);
    __builtin_amdgcn_s_setprio(1);
#pragma unroll
    for (int mi = 2; mi < 4; ++mi)
#pragma unroll
      for (int ni = 0; ni < 4; ++ni)
        acc[4 + mi][ni] = __builtin_amdgcn_mfma_f32_16x16x32_bf16(fa2[mi].v, fb[ni].v, acc[4 + mi][ni], 0, 0, 0);
    __builtin_amdgcn_s_setprio(0);
    if (T < 30) { asm volatile("s_waitcnt vmcnt(2)" ::: "memory"); }
    else        { asm volatile("s_waitcnt vmcnt(0)" ::: "memory"); }
    __builtin_amdgcn_s_barrier();
  }
#undef STAGE_A
#undef STAGE_B

  // ---- epilogue: RoPE + RMSNorm (q,k) or transposed store (v)
  const int col0 = n0 + wn * 64;   // multiple of 64 -> one head per wave
  if (z <= 1) {
    bf16* dst = z ? k_h : q_h;
#pragma unroll
    for (int mi = 0; mi < 8; ++mi)
#pragma unroll
      for (int r = 0; r < 4; ++r) {
        int row = m0 + wm * 128 + mi * 16 + quad * 4 + r;
        int s = row & (nS - 1);
        float x0 = acc[mi][0][r], x1 = acc[mi][1][r], x2 = acc[mi][2][r], x3 = acc[mi][3][r];
        float y[4];
#pragma unroll
        for (int p = 0; p < 2; ++p) {
          int d = p * 16 + l16;
          float c = __bfloat162float(cos_t[s * 32 + d]);
          float sn = __bfloat162float(sin_t[s * 32 + d]);
          float xa = p ? x1 : x0, xb = p ? x3 : x2;
          y[p] = xa * c + xb * sn;
          y[p + 2] = xb * c - xa * sn;
        }
        float ss = y[0] * y[0] + y[1] * y[1] + y[2] * y[2] + y[3] * y[3];
#pragma unroll
        for (int m = 1; m <= 8; m <<= 1) ss += __shfl_xor(ss, m, 64);
        float inv = 1.0f / sqrtf(ss * (1.0f / 64.0f) + 1e-9f);
#pragma unroll
        for (int ni = 0; ni < 4; ++ni)
          dst[(size_t)row * nD + col0 + ni * 16 + l16] = __float2bfloat16(y[ni] * inv);
      }
  } else {
    // V: write transposed -> vt_h [b][h][d][s]
#pragma unroll
    for (int mi = 0; mi < 8; ++mi)
#pragma unroll
      for (int r = 0; r < 4; ++r) {
        int row = m0 + wm * 128 + mi * 16 + quad * 4 + r;
        int b = row >> 11, s = row & (nS - 1);
#pragma unroll
        for (int ni = 0; ni < 4; ++ni) {
          int col = col0 + ni * 16 + l16;
          int h = col >> 6, d = col & 63;
          vt_h[((size_t)((b * nH + h) * 64 + d)) * nS + s] = __float2bfloat16(acc[mi][ni][r]);
        }
      }
  }
}

// ---------------------------------------------------------------- output GEMM: 64x128 tile, BK=64, grid (64, 8)
__global__ __launch_bounds__(256) void gemm_out_kernel(
    const bf16* __restrict__ A, const bf16* __restrict__ Bt, float* __restrict__ C) {
  __shared__ bf16 As[64 * 64];
  __shared__ bf16 Bs[128 * 64];
  const int t = threadIdx.x;
  const int lane = t & 63;
  const int wid = t >> 6;
  const int quad = lane >> 4;
  const int l16 = lane & 15;
  const int wm = wid >> 1;
  const int wn = wid & 1;
  const int m0 = blockIdx.x * 64;
  const int n0 = blockIdx.y * 128;
  const int K = nD;
  const int rloc = lane >> 3, cl = lane & 7;
  const int cg = cl ^ rloc;

  float4v acc[2][4] = {};
  for (int kt = 0; kt < K; kt += 64) {
    __syncthreads();
#pragma unroll
    for (int p = 0; p < 2; ++p) {
      int rowbase = (p * 4 + wid) * 8;
      gload_lds16(A + (size_t)(m0 + rowbase + rloc) * K + kt + cg * 8, As + (size_t)rowbase * 64);
    }
#pragma unroll
    for (int p = 0; p < 4; ++p) {
      int rowbase = (p * 4 + wid) * 8;
      gload_lds16(Bt + (size_t)(n0 + rowbase + rloc) * K + kt + cg * 8, Bs + (size_t)rowbase * 64);
    }
    __syncthreads();

#pragma unroll
    for (int ks = 0; ks < 2; ++ks) {
      Frag16B a[2], b[4];
#pragma unroll
      for (int mi = 0; mi < 2; ++mi) {
        int row = wm * 32 + mi * 16 + l16;
        int ch = (ks * 4 + quad) ^ (row & 7);
        a[mi].u4 = *(const uint4*)&As[row * 64 + ch * 8];
      }
#pragma unroll
      for (int ni = 0; ni < 4; ++ni) {
        int row = wn * 64 + ni * 16 + l16;
        int ch = (ks * 4 + quad) ^ (row & 7);
        b[ni].u4 = *(const uint4*)&Bs[row * 64 + ch * 8];
      }
#pragma unroll
      for (int mi = 0; mi < 2; ++mi)
#pragma unroll
        for (int ni = 0; ni < 4; ++ni)
          acc[mi][ni] = __builtin_amdgcn_mfma_f32_16x16x32_bf16(a[mi].v, b[ni].v, acc[mi][ni], 0, 0, 0);
    }
  }
#pragma unroll
  for (int mi = 0; mi < 2; ++mi)
#pragma unroll
    for (int ni = 0; ni < 4; ++ni)
#pragma unroll
      for (int r = 0; r < 4; ++r) {
        int row = m0 + wm * 32 + mi * 16 + quad * 4 + r;
        int col = n0 + wn * 64 + ni * 16 + l16;
        C[(size_t)row * nD + col] = acc[mi][ni][r];
      }
}

// ---------------------------------------------------------------- flash attention v7: 8-wave 512-thread blocks,
// wave owns 16 q-rows (1 q-slice) -> 4 waves/SIMD co-resident (2 blocks/CU) for latency hiding.
// K/V staged via global_load_lds (linear dest + pre-swizzled source; read pattern unchanged) ->
// no ds_write bank conflicts, no reg round-trip. Double-buffered; prefetch issued at iter top,
// vmcnt(0)+lgkm(0)+barrier at iter end (wait spans whole compute phase).
static constexpr float SC = 0.18033688011112042f;  // 0.125 * log2(e)

__global__ __launch_bounds__(512, 4) void attn_kernel(const bf16* __restrict__ q_h,
                                                      const bf16* __restrict__ k_h,
                                                      const bf16* __restrict__ vt_h,
                                                      bf16* __restrict__ vals) {
  __shared__ bf16 lds_buf[4 * 4096];   // [ K0 | K1 | V0 | V1 ]; front 9216 reused as epilogue scratch

  const int t = threadIdx.x;           // 0..511
  const int lane = t & 63, wid = t >> 6, quad = lane >> 4, l16 = lane & 15;
  const int id = blockIdx.x;           // 0..511
  const int xcd = id & 7;              // round-robin XCD heuristic
  const int j = id >> 3;               // 0..63 per-XCD index
  const int jj = j & 31;
  const int bh = xcd * 4 + (jj & 3);   // 4 heads per XCD; pair blocks share bh
  const int u = jj >> 2;               // 0..7
  const int qt = (j < 32) ? (15 - u) : u;   // first CU-slot: long tiles; second: complementary short
  const int b = bh >> 4, h = bh & 15;

  const bf16* Kbase = k_h + ((size_t)b * nS) * nD + h * 64;
  const bf16* Vbase = vt_h + (size_t)bh * 64 * nS;  // [d][s]

  const int rl = lane >> 3;            // 0..7
  const int cg8 = ((lane & 7) ^ rl) * 8;  // pre-swizzled source chunk (elem offset)
  const int srow = wid * 8 + rl;       // 0..63: this lane's staging row
  const int r7 = l16 & 7;

  bf16* const scratch = lds_buf + wid * 1152;  // 16 x 72 per wave

  const int nkt = 2 * qt + 2;
  const int q0w = qt * 128 + wid * 16;         // wave's first q row

  // Q B-frags (col=q=l16, k=d), 2 d-halves
  Frag16B qf[2];
  {
    const bf16* qp = q_h + ((size_t)(b * nS + q0w + l16)) * nD + h * 64;
    qf[0].u4 = *(const uint4*)(qp + quad * 8);
    qf[1].u4 = *(const uint4*)(qp + 32 + quad * 8);
  }

  // stage K/V tile KT into buffer (KT&1): linear LDS dest (wave-uniform base), swizzled source
#define STAGE_KV(KT) do { \
    const int bo_ = ((KT) & 1) * 4096; \
    gload_lds16(Kbase + (size_t)((KT) * 64 + srow) * nD + cg8, lds_buf + bo_ + wid * 512); \
    gload_lds16(Vbase + (size_t)srow * nS + (KT) * 64 + cg8, lds_buf + 8192 + bo_ + wid * 512); \
  } while (0)

  STAGE_KV(0);
  asm volatile("s_waitcnt vmcnt(0)" ::: "memory");
  __builtin_amdgcn_s_barrier();

  float4v o_acc[4] = {};
  float l_acc = 0.f;

  for (int kt = 0; kt < nkt; ++kt) {
    // prefetch next tile into the buffer everyone finished reading before the last barrier
    if (kt + 1 < nkt) STAGE_KV(kt + 1);

    const bf16* Kb = lds_buf + (kt & 1) * 4096;
    const bf16* Vb = lds_buf + 8192 + (kt & 1) * 4096;

    if (kt * 64 <= q0w + 15) {   // wave has unmasked keys in this tile
      // S^T[key][q]; K frags as A-operand (k=d), Q frags as B
      float4v st[4];
      __builtin_amdgcn_s_setprio(1);
#pragma unroll
      for (int kt4 = 0; kt4 < 4; ++kt4) {
        int row = kt4 * 16 + l16;
        Frag16B k0, k1;
        k0.u4 = *(const uint4*)&Kb[row * 64 + ((quad ^ r7) * 8)];
        k1.u4 = *(const uint4*)&Kb[row * 64 + (((quad + 4) ^ r7) * 8)];
        float4v zz = {};
        zz = __builtin_amdgcn_mfma_f32_16x16x32_bf16(k0.v, qf[0].v, zz, 0, 0, 0);
        st[kt4] = __builtin_amdgcn_mfma_f32_16x16x32_bf16(k1.v, qf[1].v, zz, 0, 0, 0);
      }
      __builtin_amdgcn_s_setprio(0);

      // exp + pack P^T B-frags (k=key=quad*4+r == C-layout row)
      short4v pf[4];
      const bool need_mask = (kt * 64 + 63) > q0w;   // wave-uniform
      if (need_mask) {
        int qg = q0w + l16;
#pragma unroll
        for (int kt4 = 0; kt4 < 4; ++kt4) {
          int key0 = kt * 64 + kt4 * 16 + quad * 4;
#pragma unroll
          for (int r = 0; r < 4; ++r) {
            float x = st[kt4][r] * SC;
            if (key0 + r > qg) x = -12000.0f;
            float p = fast_exp2(x);
            l_acc += p;
            union { bf16 hh; short ss; } cv;
            cv.hh = __float2bfloat16(p);
            pf[kt4][r] = cv.ss;
          }
        }
      } else {
#pragma unroll
        for (int kt4 = 0; kt4 < 4; ++kt4)
#pragma unroll
          for (int r = 0; r < 4; ++r) {
            float p = fast_exp2(st[kt4][r] * SC);
            l_acc += p;
            union { bf16 hh; short ss; } cv;
            cv.hh = __float2bfloat16(p);
            pf[kt4][r] = cv.ss;
          }
      }

      // O^T[d][q] += V^T·P^T
      __builtin_amdgcn_s_setprio(1);
#pragma unroll
      for (int dt = 0; dt < 4; ++dt) {
        int row = dt * 16 + l16;
#pragma unroll
        for (int kt4 = 0; kt4 < 4; ++kt4) {
          int chunk = kt4 * 2 + (quad >> 1);
          union { uint2 u; short4v s; } vv;
          vv.u = *(const uint2*)&Vb[row * 64 + ((chunk ^ r7) * 8) + (quad & 1) * 4];
          o_acc[dt] = __builtin_amdgcn_mfma_f32_16x16x16bf16_1k(vv.s, pf[kt4], o_acc[dt], 0, 0, 0);
        }
      }
      __builtin_amdgcn_s_setprio(0);
    }

    // prefetch landed + own ds_reads drained, then barrier: next iter's buffer is ready & free
    asm volatile("s_waitcnt vmcnt(0) lgkmcnt(0)" ::: "memory");
    __builtin_amdgcn_s_barrier();
  }
#undef STAGE_KV

  // ---- epilogue: row-sum reduce, LDS-transpose, coalesced 16B stores
  float la = l_acc;
  la += __shfl_xor(la, 16, 64);
  la += __shfl_xor(la, 32, 64);
  float inv_l = 1.0f / la;
  // write transposed: scratch[q_loc=l16][d]
#pragma unroll
  for (int dt = 0; dt < 4; ++dt) {
    union { bf16 b2[2]; uint u; } p01, p23;
    p01.b2[0] = __float2bfloat16(o_acc[dt][0] * inv_l);
    p01.b2[1] = __float2bfloat16(o_acc[dt][1] * inv_l);
    p23.b2[0] = __float2bfloat16(o_acc[dt][2] * inv_l);
    p23.b2[1] = __float2bfloat16(o_acc[dt][3] * inv_l);
    *(uint*)&scratch[l16 * 72 + dt * 16 + quad * 4] = p01.u;
    *(uint*)&scratch[l16 * 72 + dt * 16 + quad * 4 + 2] = p23.u;
  }
  lgkm_wait();  // own writes visible to own reads
  uint4 r0 = *(const uint4*)&scratch[l16 * 72 + quad * 16];
  uint4 r1 = *(const uint4*)&scratch[l16 * 72 + quad * 16 + 8];
  int qrow = q0w + l16;
  bf16* vp = vals + ((size_t)(b * nS + qrow)) * nD + h * 64 + quad * 16;
  *(uint4*)(vp) = r0;
  *(uint4*)(vp + 8) = r1;
}

// ---------------------------------------------------------------- launch
extern "C" void kernel_launch(void* const* d_in, const int* in_sizes, int n_in,
                              void* d_out, int out_size, void* d_ws, size_t ws_size,
                              hipStream_t stream) {
  const float* Qin = (const float*)d_in[0];
  const float* Kin = (const float*)d_in[1];
  const float* Vin = (const float*)d_in[2];
  const float* Wq = (const float*)d_in[4];
  const float* Wk = (const float*)d_in[5];
  const float* Wv = (const float*)d_in[6];
  const float* Wo = (const float*)d_in[7];
  float* out = (float*)d_out;

  char* ws = (char*)d_ws;
  const size_t MB = 1u << 20;
  bf16* Qbf = (bf16*)(ws + 0 * MB);
  bf16* Kbf = (bf16*)(ws + 8 * MB);
  bf16* Vbf = (bf16*)(ws + 16 * MB);
  bf16* WqT = (bf16*)(ws + 24 * MB);
  bf16* WkT = (bf16*)(ws + 26 * MB);
  bf16* WvT = (bf16*)(ws + 28 * MB);
  bf16* WoT = (bf16*)(ws + 30 * MB);
  bf16* cos_t = (bf16*)(ws + 32 * MB);
  bf16* sin_t = (bf16*)(ws + 33 * MB);
  bf16* q_h = (bf16*)(ws + 34 * MB);
  bf16* k_h = (bf16*)(ws + 42 * MB);
  bf16* vt_h = (bf16*)(ws + 50 * MB);
  bf16* vals = (bf16*)(ws + 58 * MB);

  prep_kernel<<<4160, 256, 0, stream>>>(Qin, Kin, Vin, Wq, Wk, Wv, Wo,
                                        Qbf, Kbf, Vbf, WqT, WkT, WvT, WoT, cos_t, sin_t);

  gemm_qkv_kernel<<<dim3(16, 4, 3), 512, 0, stream>>>(Qbf, Kbf, Vbf, WqT, WkT, WvT,
                                                      q_h, k_h, vt_h, cos_t, sin_t);

  attn_kernel<<<512, 512, 0, stream>>>(q_h, k_h, vt_h, vals);

  gemm_out_kernel<<<dim3(64, 8), 256, 0, stream>>>(vals, WoT, out);
}

// Round 5
// 213.925 us; speedup vs baseline: 1.1275x; 1.0433x over previous
//
#include <hip/hip_runtime.h>
#include <hip/hip_bf16.h>
#include <stdint.h>

typedef __hip_bfloat16 bf16;
typedef __attribute__((ext_vector_type(8))) short short8;
typedef __attribute__((ext_vector_type(4))) short short4v;
typedef __attribute__((ext_vector_type(4))) float float4v;

static constexpr int nB = 2, nS = 2048, nD = 1024, nH = 16, nHD = 64;
static constexpr int nBS = nB * nS;   // 4096

#define AS_GLOBAL __attribute__((address_space(1)))
#define AS_LDS    __attribute__((address_space(3)))

union Frag16B { short8 v; uint4 u4; uint2 u2[2]; };

__device__ __forceinline__ void gload_lds16(const void* g, void* l) {
  __builtin_amdgcn_global_load_lds((AS_GLOBAL uint32_t*)(g), (AS_LDS uint32_t*)(l), 16, 0, 0);
}

__device__ __forceinline__ float fast_exp2(float x) {
#if __has_builtin(__builtin_amdgcn_exp2f)
  return __builtin_amdgcn_exp2f(x);
#else
  float r; asm volatile("v_exp_f32 %0, %1" : "=v"(r) : "v"(x)); return r;
#endif
}

// drain LDS ops but NOT vmem: prefetch global loads stay in flight across the barrier
__device__ __forceinline__ void lds_barrier() {
  asm volatile("s_waitcnt lgkmcnt(0)\ns_barrier" ::: "memory");
}

__device__ __forceinline__ void lgkm_wait() {
  asm volatile("s_waitcnt lgkmcnt(0)" ::: "memory");
}

// ---------------------------------------------------------------- prep: cast QKV->bf16, W->W^T bf16, rope tables
__global__ __launch_bounds__(256) void prep_kernel(
    const float* __restrict__ Qin, const float* __restrict__ Kin, const float* __restrict__ Vin,
    const float* __restrict__ Wq, const float* __restrict__ Wk,
    const float* __restrict__ Wv, const float* __restrict__ Wo,
    bf16* __restrict__ Qbf, bf16* __restrict__ Kbf, bf16* __restrict__ Vbf,
    bf16* __restrict__ WqT, bf16* __restrict__ WkT, bf16* __restrict__ WvT, bf16* __restrict__ WoT,
    bf16* __restrict__ cos_t, bf16* __restrict__ sin_t) {
  __shared__ float tile[64][65];
  int bx = blockIdx.x, t = threadIdx.x;
  if (bx < 3072) {
    int tz = bx >> 10, blk = bx & 1023;
    const float* src = tz == 0 ? Qin : tz == 1 ? Kin : Vin;
    bf16* dst = tz == 0 ? Qbf : tz == 1 ? Kbf : Vbf;
#pragma unroll
    for (int i = 0; i < 4; ++i) {
      int idx = blk * 1024 + i * 256 + t;  // float4 index
      float4 v = ((const float4*)src)[idx];
      union { bf16 b[4]; uint2 u; } tmp;
      tmp.b[0] = __float2bfloat16(v.x);
      tmp.b[1] = __float2bfloat16(v.y);
      tmp.b[2] = __float2bfloat16(v.z);
      tmp.b[3] = __float2bfloat16(v.w);
      ((uint2*)dst)[idx] = tmp.u;
    }
  } else if (bx < 4096) {
    int idx = bx - 3072;
    int z = idx >> 8;
    const float* W = z == 0 ? Wq : z == 1 ? Wk : z == 2 ? Wv : Wo;
    bf16* T = z == 0 ? WqT : z == 1 ? WkT : z == 2 ? WvT : WoT;
    int tk = (idx & 15) * 64, tn = ((idx >> 4) & 15) * 64;
    int c = t & 63, r0 = t >> 6;
#pragma unroll
    for (int i = 0; i < 16; ++i) {
      int r = i * 4 + r0;
      tile[r][c] = W[(size_t)(tk + r) * nD + tn + c];
    }
    __syncthreads();
#pragma unroll
    for (int i = 0; i < 16; ++i) {
      int r = i * 4 + r0;
      T[(size_t)(tn + r) * nD + tk + c] = __float2bfloat16(tile[c][r]);
    }
  } else {
    int base = (bx - 4096) * 1024 + t * 4;
#pragma unroll
    for (int i = 0; i < 4; ++i) {
      int e = base + i;
      int s = e >> 5, j = e & 31;
      float inv_freq = powf(100000.0f, -(float)(2 * j) / 64.0f);
      float g = (float)s * inv_freq;
      cos_t[e] = __float2bfloat16(cosf(g));
      sin_t[e] = __float2bfloat16(sinf(g));
    }
  }
}

// ---------------------------------------------------------------- fused projection GEMM, 256x256 tile, BK=32,
// 8 waves (2Mx4N), double-buffered 64 KiB LDS, 3-phase interleave with counted vmcnt.
__global__ __launch_bounds__(512, 2) void gemm_qkv_kernel(
    const bf16* __restrict__ A0, const bf16* __restrict__ A1, const bf16* __restrict__ A2,
    const bf16* __restrict__ Bt0, const bf16* __restrict__ Bt1, const bf16* __restrict__ Bt2,
    bf16* __restrict__ q_h, bf16* __restrict__ k_h, bf16* __restrict__ vt_h,
    const bf16* __restrict__ cos_t, const bf16* __restrict__ sin_t) {
  const int z = blockIdx.z;
  const bf16* __restrict__ A  = z == 0 ? A0 : (z == 1 ? A1 : A2);
  const bf16* __restrict__ Bt = z == 0 ? Bt0 : (z == 1 ? Bt1 : Bt2);

  __shared__ bf16 As[2 * 256 * 32];   // 32 KiB (two 16 KiB buffers)
  __shared__ bf16 Bs[2 * 256 * 32];   // 32 KiB

  const int t = threadIdx.x;          // 0..511
  const int lane = t & 63;
  const int wid = t >> 6;             // 0..7
  const int quad = lane >> 4;
  const int l16 = lane & 15;
  const int wm = wid >> 2;            // 0..1 -> 128 rows each
  const int wn = wid & 3;             // 0..3 -> 64 cols each (one head per wave)
  const int m0 = blockIdx.x * 256;    // 16 m-tiles
  const int n0 = blockIdx.y * 256;    // 4 n-tiles

  // staging constants: linear LDS dest (wave-uniform base + lane*16B), pre-swizzled global source
  const int sc    = (t & 7) ^ ((t >> 3) & 7);   // c_orig for this lane's 16B chunk
  const int sml   = 2 * (t >> 3) + (sc >> 2);   // m row within 128-row half
  const int skoff = (sc & 3) * 8;               // k element offset
  const int swave = wid * 512;                  // wave-uniform LDS elem base within half

  // fragment-read constants
  const int R0a = wm * 64 + (l16 >> 1);
  const int R0b = wn * 32 + (l16 >> 1);
  const int cpar = (l16 & 1) * 4;
  const int abase = R0a * 64 + (((cpar + quad) ^ (R0a & 7)) * 8);  // + mi*512 (+buf)
  const int bbase = R0b * 64 + (((cpar + quad) ^ (R0b & 7)) * 8);  // + ni*512 (+buf)

#define STAGE_A(KT, BUF) do { \
    const bf16* ag_ = A + (size_t)(m0 + sml) * nD + (KT) * 32 + skoff; \
    gload_lds16(ag_, As + (BUF) + swave); \
    gload_lds16(ag_ + (size_t)128 * nD, As + (BUF) + 4096 + swave); \
  } while (0)
#define STAGE_B(KT, BUF) do { \
    const bf16* bg_ = Bt + (size_t)(n0 + sml) * nD + (KT) * 32 + skoff; \
    gload_lds16(bg_, Bs + (BUF) + swave); \
    gload_lds16(bg_ + (size_t)128 * nD, Bs + (BUF) + 4096 + swave); \
  } while (0)

  float4v acc[8][4] = {};

  // prologue: A(0),B(0) -> buf0; A(1) -> buf1; vmcnt(2) leaves A(1) in flight
  STAGE_A(0, 0);
  STAGE_B(0, 0);
  STAGE_A(1, 8192);
  asm volatile("s_waitcnt vmcnt(2)" ::: "memory");
  __builtin_amdgcn_s_barrier();

#pragma unroll 2
  for (int T = 0; T < 32; ++T) {
    const int cu = (T & 1) * 8192;
    const int nx = cu ^ 8192;

    // ---- phase 0
    if (T < 31) STAGE_B(T + 1, nx);
    Frag16B fa[4], fb[4];
#pragma unroll
    for (int mi = 0; mi < 4; ++mi) fa[mi].u4 = *(const uint4*)&As[cu + abase + mi * 512];
#pragma unroll
    for (int ni = 0; ni < 4; ++ni) fb[ni].u4 = *(const uint4*)&Bs[cu + bbase + ni * 512];
    __builtin_amdgcn_s_setprio(1);
#pragma unroll
    for (int mi = 0; mi < 4; ++mi)
#pragma unroll
      for (int ni = 0; ni < 4; ++ni)
        acc[mi][ni] = __builtin_amdgcn_mfma_f32_16x16x32_bf16(fa[mi].v, fb[ni].v, acc[mi][ni], 0, 0, 0);
    __builtin_amdgcn_s_setprio(0);
    __builtin_amdgcn_s_barrier();

    // ---- phase 1: last reads of cu; drain; barrier => every wave done reading cu
    Frag16B fa2[4];
#pragma unroll
    for (int mi = 0; mi < 4; ++mi) fa2[mi].u4 = *(const uint4*)&As[cu + abase + (mi + 4) * 512];
    asm volatile("s_waitcnt lgkmcnt(0)" ::: "memory");
    __builtin_amdgcn_s_setprio(1);
#pragma unroll
    for (int mi = 0; mi < 2; ++mi)
#pragma unroll
      for (int ni = 0; ni < 4; ++ni)
        acc[4 + mi][ni] = __builtin_amdgcn_mfma_f32_16x16x32_bf16(fa2[mi].v, fb[ni].v, acc[4 + mi][ni], 0, 0, 0);
    __builtin_amdgcn_s_setprio(0);
    __builtin_amdgcn_s_barrier();

    // ---- phase 2: stage A(T+2) into cu (drained); counted vmcnt
    if (T < 30) STAGE_A(T + 2, cu);
    __builtin_amdgcn_s_setprio(1);
#pragma unroll
    for (int mi = 2; mi < 4; ++mi)
#pragma unroll
      for (int ni = 0; ni < 4; ++ni)
        acc[4 + mi][ni] = __builtin_amdgcn_mfma_f32_16x16x32_bf16(fa2[mi].v, fb[ni].v, acc[4 + mi][ni], 0, 0, 0);
    __builtin_amdgcn_s_setprio(0);
    if (T < 30) { asm volatile("s_waitcnt vmcnt(2)" ::: "memory"); }
    else        { asm volatile("s_waitcnt vmcnt(0)" ::: "memory"); }
    __builtin_amdgcn_s_barrier();
  }
#undef STAGE_A
#undef STAGE_B

  // ---- epilogue: RoPE + RMSNorm (q,k) or transposed store (v)
  const int col0 = n0 + wn * 64;   // multiple of 64 -> one head per wave
  if (z <= 1) {
    bf16* dst = z ? k_h : q_h;
#pragma unroll
    for (int mi = 0; mi < 8; ++mi)
#pragma unroll
      for (int r = 0; r < 4; ++r) {
        int row = m0 + wm * 128 + mi * 16 + quad * 4 + r;
        int s = row & (nS - 1);
        float x0 = acc[mi][0][r], x1 = acc[mi][1][r], x2 = acc[mi][2][r], x3 = acc[mi][3][r];
        float y[4];
#pragma unroll
        for (int p = 0; p < 2; ++p) {
          int d = p * 16 + l16;
          float c = __bfloat162float(cos_t[s * 32 + d]);
          float sn = __bfloat162float(sin_t[s * 32 + d]);
          float xa = p ? x1 : x0, xb = p ? x3 : x2;
          y[p] = xa * c + xb * sn;
          y[p + 2] = xb * c - xa * sn;
        }
        float ss = y[0] * y[0] + y[1] * y[1] + y[2] * y[2] + y[3] * y[3];
#pragma unroll
        for (int m = 1; m <= 8; m <<= 1) ss += __shfl_xor(ss, m, 64);
        float inv = 1.0f / sqrtf(ss * (1.0f / 64.0f) + 1e-9f);
#pragma unroll
        for (int ni = 0; ni < 4; ++ni)
          dst[(size_t)row * nD + col0 + ni * 16 + l16] = __float2bfloat16(y[ni] * inv);
      }
  } else {
    // V: write transposed -> vt_h [b][h][d][s]
#pragma unroll
    for (int mi = 0; mi < 8; ++mi)
#pragma unroll
      for (int r = 0; r < 4; ++r) {
        int row = m0 + wm * 128 + mi * 16 + quad * 4 + r;
        int b = row >> 11, s = row & (nS - 1);
#pragma unroll
        for (int ni = 0; ni < 4; ++ni) {
          int col = col0 + ni * 16 + l16;
          int h = col >> 6, d = col & 63;
          vt_h[((size_t)((b * nH + h) * 64 + d)) * nS + s] = __float2bfloat16(acc[mi][ni][r]);
        }
      }
  }
}

// ---------------------------------------------------------------- output GEMM: 64x128 tile, BK=64, grid (64, 8)
__global__ __launch_bounds__(256) void gemm_out_kernel(
    const bf16* __restrict__ A, const bf16* __restrict__ Bt, float* __restrict__ C) {
  __shared__ bf16 As[64 * 64];
  __shared__ bf16 Bs[128 * 64];
  const int t = threadIdx.x;
  const int lane = t & 63;
  const int wid = t >> 6;
  const int quad = lane >> 4;
  const int l16 = lane & 15;
  const int wm = wid >> 1;
  const int wn = wid & 1;
  const int m0 = blockIdx.x * 64;
  const int n0 = blockIdx.y * 128;
  const int K = nD;
  const int rloc = lane >> 3, cl = lane & 7;
  const int cg = cl ^ rloc;

  float4v acc[2][4] = {};
  for (int kt = 0; kt < K; kt += 64) {
    __syncthreads();
#pragma unroll
    for (int p = 0; p < 2; ++p) {
      int rowbase = (p * 4 + wid) * 8;
      gload_lds16(A + (size_t)(m0 + rowbase + rloc) * K + kt + cg * 8, As + (size_t)rowbase * 64);
    }
#pragma unroll
    for (int p = 0; p < 4; ++p) {
      int rowbase = (p * 4 + wid) * 8;
      gload_lds16(Bt + (size_t)(n0 + rowbase + rloc) * K + kt + cg * 8, Bs + (size_t)rowbase * 64);
    }
    __syncthreads();

#pragma unroll
    for (int ks = 0; ks < 2; ++ks) {
      Frag16B a[2], b[4];
#pragma unroll
      for (int mi = 0; mi < 2; ++mi) {
        int row = wm * 32 + mi * 16 + l16;
        int ch = (ks * 4 + quad) ^ (row & 7);
        a[mi].u4 = *(const uint4*)&As[row * 64 + ch * 8];
      }
#pragma unroll
      for (int ni = 0; ni < 4; ++ni) {
        int row = wn * 64 + ni * 16 + l16;
        int ch = (ks * 4 + quad) ^ (row & 7);
        b[ni].u4 = *(const uint4*)&Bs[row * 64 + ch * 8];
      }
#pragma unroll
      for (int mi = 0; mi < 2; ++mi)
#pragma unroll
        for (int ni = 0; ni < 4; ++ni)
          acc[mi][ni] = __builtin_amdgcn_mfma_f32_16x16x32_bf16(a[mi].v, b[ni].v, acc[mi][ni], 0, 0, 0);
    }
  }
#pragma unroll
  for (int mi = 0; mi < 2; ++mi)
#pragma unroll
    for (int ni = 0; ni < 4; ++ni)
#pragma unroll
      for (int r = 0; r < 4; ++r) {
        int row = m0 + wm * 32 + mi * 16 + quad * 4 + r;
        int col = n0 + wn * 64 + ni * 16 + l16;
        C[(size_t)row * nD + col] = acc[mi][ni][r];
      }
}

// ---------------------------------------------------------------- flash attention v8: KVBLK=128, 8-wave blocks,
// wave owns 16 q-rows. Main loop = full unmasked 128-key tiles (branchless single basic block:
// QK(h0),QK(h1),exp(h0),PV(h0),exp(h1),PV(h1) -> exp VALU overlaps MFMA); final diagonal tile
// handles all masking. K/V via global_load_lds (linear dest, pre-swizzled source), double-buffered
// 64 KiB LDS (2 blocks/CU), one vmcnt(0)+lgkm(0)+barrier per 128 keys.
static constexpr float SC = 0.18033688011112042f;  // 0.125 * log2(e)

__global__ __launch_bounds__(512, 4) void attn_kernel(const bf16* __restrict__ q_h,
                                                      const bf16* __restrict__ k_h,
                                                      const bf16* __restrict__ vt_h,
                                                      bf16* __restrict__ vals) {
  __shared__ bf16 lds_buf[4 * 8192];   // [K0|K1|V0|V1], 8192 elems each: K=128x64, V=2 half-subtiles 64x64

  const int t = threadIdx.x;           // 0..511
  const int lane = t & 63, wid = t >> 6, quad = lane >> 4, l16 = lane & 15;
  const int id = blockIdx.x;           // 0..511
  const int xcd = id & 7;              // round-robin XCD heuristic
  const int j = id >> 3;               // 0..63 per-XCD index
  const int jj = j & 31;
  const int bh = xcd * 4 + (jj & 3);   // 4 heads per XCD; pair blocks share bh
  const int u = jj >> 2;               // 0..7
  const int qt = (j < 32) ? (15 - u) : u;   // first CU-slot: long tiles; second: complementary short
  const int b = bh >> 4, h = bh & 15;

  const bf16* Kbase = k_h + ((size_t)b * nS) * nD + h * 64;
  const bf16* Vbase = vt_h + (size_t)bh * 64 * nS;  // [d][s]

  const int rl = lane >> 3;               // 0..7
  const int cg8 = ((lane & 7) ^ rl) * 8;  // pre-swizzled source chunk (elem offset)
  const int r7 = l16 & 7;

  bf16* const scratch = lds_buf + wid * 1152;  // 16 x 72 per wave (epilogue only)

  const int q0w = qt * 128 + wid * 16;         // wave's first q row

  // Q B-frags (col=q=l16, k=d), 2 d-halves
  Frag16B qf[2];
  {
    const bf16* qp = q_h + ((size_t)(b * nS + q0w + l16)) * nD + h * 64;
    qf[0].u4 = *(const uint4*)(qp + quad * 8);
    qf[1].u4 = *(const uint4*)(qp + 32 + quad * 8);
  }

  // stage 128-key K/V tile KT into buffer (KT&1): linear LDS dest, swizzled global source
#define STAGE_KV(KT) do { \
    const int bo_ = ((KT) & 1) * 8192; \
    const bf16* kg_ = Kbase + (size_t)((KT) * 128 + wid * 16 + rl) * nD + cg8; \
    gload_lds16(kg_, lds_buf + bo_ + wid * 1024); \
    gload_lds16(kg_ + (size_t)8 * nD, lds_buf + bo_ + wid * 1024 + 512); \
    const bf16* vg_ = Vbase + (size_t)(wid * 8 + rl) * nS + (KT) * 128 + cg8; \
    gload_lds16(vg_, lds_buf + 16384 + bo_ + wid * 512); \
    gload_lds16(vg_ + 64, lds_buf + 16384 + bo_ + 4096 + wid * 512); \
  } while (0)

  // QK^T for half HB of current K tile -> ST (S^T frags, key=row)
#define QKH(Kb, HB, ST) do { \
    _Pragma("unroll") \
    for (int kt4 = 0; kt4 < 4; ++kt4) { \
      int row = (HB) * 64 + kt4 * 16 + l16; \
      Frag16B k0_, k1_; \
      k0_.u4 = *(const uint4*)&(Kb)[row * 64 + ((quad ^ r7) * 8)]; \
      k1_.u4 = *(const uint4*)&(Kb)[row * 64 + (((quad + 4) ^ r7) * 8)]; \
      float4v zz_ = {}; \
      zz_ = __builtin_amdgcn_mfma_f32_16x16x32_bf16(k0_.v, qf[0].v, zz_, 0, 0, 0); \
      (ST)[kt4] = __builtin_amdgcn_mfma_f32_16x16x32_bf16(k1_.v, qf[1].v, zz_, 0, 0, 0); \
    } \
  } while (0)

  // exp (unmasked) ST -> PF, accumulate l_acc
#define EXPH(ST, PF) do { \
    _Pragma("unroll") \
    for (int kt4 = 0; kt4 < 4; ++kt4) \
      _Pragma("unroll") \
      for (int r = 0; r < 4; ++r) { \
        float p_ = fast_exp2((ST)[kt4][r] * SC); \
        l_acc += p_; \
        union { bf16 hh; short ss; } cv_; \
        cv_.hh = __float2bfloat16(p_); \
        (PF)[kt4][r] = cv_.ss; \
      } \
  } while (0)

  // exp (masked, diagonal tile) for half HB
#define EXPHM(ST, PF, HB) do { \
    int qg_ = q0w + l16; \
    _Pragma("unroll") \
    for (int kt4 = 0; kt4 < 4; ++kt4) { \
      int key0_ = qt * 128 + (HB) * 64 + kt4 * 16 + quad * 4; \
      _Pragma("unroll") \
      for (int r = 0; r < 4; ++r) { \
        float x_ = (ST)[kt4][r] * SC; \
        if (key0_ + r > qg_) x_ = -12000.0f; \
        float p_ = fast_exp2(x_); \
        l_acc += p_; \
        union { bf16 hh; short ss; } cv_; \
        cv_.hh = __float2bfloat16(p_); \
        (PF)[kt4][r] = cv_.ss; \
      } \
    } \
  } while (0)

  // O^T += V^T(half HB) . P^T
#define PVH(Vb, HB, PF) do { \
    _Pragma("unroll") \
    for (int dt = 0; dt < 4; ++dt) { \
      int row = dt * 16 + l16; \
      _Pragma("unroll") \
      for (int kt4 = 0; kt4 < 4; ++kt4) { \
        int chunk_ = kt4 * 2 + (quad >> 1); \
        union { uint2 u; short4v s; } vv_; \
        vv_.u = *(const uint2*)&(Vb)[(HB) * 4096 + row * 64 + ((chunk_ ^ r7) * 8) + (quad & 1) * 4]; \
        o_acc[dt] = __builtin_amdgcn_mfma_f32_16x16x16bf16_1k(vv_.s, (PF)[kt4], o_acc[dt], 0, 0, 0); \
      } \
    } \
  } while (0)

  STAGE_KV(0);
  asm volatile("s_waitcnt vmcnt(0)" ::: "memory");
  __builtin_amdgcn_s_barrier();

  float4v o_acc[4] = {};
  float l_acc = 0.f;

  // ---- main loop: full unmasked tiles (branchless)
  for (int kt = 0; kt < qt; ++kt) {
    STAGE_KV(kt + 1);
    const bf16* Kb = lds_buf + (kt & 1) * 8192;
    const bf16* Vb = lds_buf + 16384 + (kt & 1) * 8192;

    float4v st0[4], st1[4];
    __builtin_amdgcn_s_setprio(1);
    QKH(Kb, 0, st0);
    QKH(Kb, 1, st1);
    __builtin_amdgcn_s_setprio(0);

    short4v pf[4];
    EXPH(st0, pf);
    __builtin_amdgcn_s_setprio(1);
    PVH(Vb, 0, pf);
    __builtin_amdgcn_s_setprio(0);
    EXPH(st1, pf);
    __builtin_amdgcn_s_setprio(1);
    PVH(Vb, 1, pf);
    __builtin_amdgcn_s_setprio(0);

    asm volatile("s_waitcnt vmcnt(0) lgkmcnt(0)" ::: "memory");
    __builtin_amdgcn_s_barrier();
  }

  // ---- final diagonal tile kt = qt (no prefetch; all masking lives here)
  {
    const bf16* Kb = lds_buf + (qt & 1) * 8192;
    const bf16* Vb = lds_buf + 16384 + (qt & 1) * 8192;

    float4v st0[4];
    QKH(Kb, 0, st0);
    short4v pf[4];
    EXPHM(st0, pf, 0);
    PVH(Vb, 0, pf);

    if (wid >= 4) {   // waves 0-3: h1 keys are all > q0w+15 (fully masked) -> skip
      float4v st1[4];
      QKH(Kb, 1, st1);
      EXPHM(st1, pf, 1);
      PVH(Vb, 1, pf);
    }
  }
#undef STAGE_KV
#undef QKH
#undef EXPH
#undef EXPHM
#undef PVH

  // all waves done reading K/V before scratch (overlapping K region) is overwritten
  lds_barrier();

  // ---- epilogue: row-sum reduce, LDS-transpose, coalesced 16B stores
  float la = l_acc;
  la += __shfl_xor(la, 16, 64);
  la += __shfl_xor(la, 32, 64);
  float inv_l = 1.0f / la;
  // write transposed: scratch[q_loc=l16][d]
#pragma unroll
  for (int dt = 0; dt < 4; ++dt) {
    union { bf16 b2[2]; uint u; } p01, p23;
    p01.b2[0] = __float2bfloat16(o_acc[dt][0] * inv_l);
    p01.b2[1] = __float2bfloat16(o_acc[dt][1] * inv_l);
    p23.b2[0] = __float2bfloat16(o_acc[dt][2] * inv_l);
    p23.b2[1] = __float2bfloat16(o_acc[dt][3] * inv_l);
    *(uint*)&scratch[l16 * 72 + dt * 16 + quad * 4] = p01.u;
    *(uint*)&scratch[l16 * 72 + dt * 16 + quad * 4 + 2] = p23.u;
  }
  lgkm_wait();  // own writes visible to own reads
  uint4 r0 = *(const uint4*)&scratch[l16 * 72 + quad * 16];
  uint4 r1 = *(const uint4*)&scratch[l16 * 72 + quad * 16 + 8];
  int qrow = q0w + l16;
  bf16* vp = vals + ((size_t)(b * nS + qrow)) * nD + h * 64 + quad * 16;
  *(uint4*)(vp) = r0;
  *(uint4*)(vp + 8) = r1;
}

// ---------------------------------------------------------------- launch
extern "C" void kernel_launch(void* const* d_in, const int* in_sizes, int n_in,
                              void* d_out, int out_size, void* d_ws, size_t ws_size,
                              hipStream_t stream) {
  const float* Qin = (const float*)d_in[0];
  const float* Kin = (const float*)d_in[1];
  const float* Vin = (const float*)d_in[2];
  const float* Wq = (const float*)d_in[4];
  const float* Wk = (const float*)d_in[5];
  const float* Wv = (const float*)d_in[6];
  const float* Wo = (const float*)d_in[7];
  float* out = (float*)d_out;

  char* ws = (char*)d_ws;
  const size_t MB = 1u << 20;
  bf16* Qbf = (bf16*)(ws + 0 * MB);
  bf16* Kbf = (bf16*)(ws + 8 * MB);
  bf16* Vbf = (bf16*)(ws + 16 * MB);
  bf16* WqT = (bf16*)(ws + 24 * MB);
  bf16* WkT = (bf16*)(ws + 26 * MB);
  bf16* WvT = (bf16*)(ws + 28 * MB);
  bf16* WoT = (bf16*)(ws + 30 * MB);
  bf16* cos_t = (bf16*)(ws + 32 * MB);
  bf16* sin_t = (bf16*)(ws + 33 * MB);
  bf16* q_h = (bf16*)(ws + 34 * MB);
  bf16* k_h = (bf16*)(ws + 42 * MB);
  bf16* vt_h = (bf16*)(ws + 50 * MB);
  bf16* vals = (bf16*)(ws + 58 * MB);

  prep_kernel<<<4160, 256, 0, stream>>>(Qin, Kin, Vin, Wq, Wk, Wv, Wo,
                                        Qbf, Kbf, Vbf, WqT, WkT, WvT, WoT, cos_t, sin_t);

  gemm_qkv_kernel<<<dim3(16, 4, 3), 512, 0, stream>>>(Qbf, Kbf, Vbf, WqT, WkT, WvT,
                                                      q_h, k_h, vt_h, cos_t, sin_t);

  attn_kernel<<<512, 512, 0, stream>>>(q_h, k_h, vt_h, vals);

  gemm_out_kernel<<<dim3(64, 8), 256, 0, stream>>>(vals, WoT, out);
}

// Round 6
// 208.897 us; speedup vs baseline: 1.1546x; 1.0241x over previous
//
#include <hip/hip_runtime.h>
#include <hip/hip_bf16.h>
#include <stdint.h>

typedef __hip_bfloat16 bf16;
typedef __attribute__((ext_vector_type(8))) short short8;
typedef __attribute__((ext_vector_type(4))) short short4v;
typedef __attribute__((ext_vector_type(4))) float float4v;

static constexpr int nB = 2, nS = 2048, nD = 1024, nH = 16, nHD = 64;
static constexpr int nBS = nB * nS;   // 4096

#define AS_GLOBAL __attribute__((address_space(1)))
#define AS_LDS    __attribute__((address_space(3)))

union Frag16B { short8 v; uint4 u4; uint2 u2[2]; };

__device__ __forceinline__ void gload_lds16(const void* g, void* l) {
  __builtin_amdgcn_global_load_lds((AS_GLOBAL uint32_t*)(g), (AS_LDS uint32_t*)(l), 16, 0, 0);
}

__device__ __forceinline__ float fast_exp2(float x) {
#if __has_builtin(__builtin_amdgcn_exp2f)
  return __builtin_amdgcn_exp2f(x);
#else
  float r; asm volatile("v_exp_f32 %0, %1" : "=v"(r) : "v"(x)); return r;
#endif
}

// drain LDS ops but NOT vmem: prefetch global loads stay in flight across the barrier
__device__ __forceinline__ void lds_barrier() {
  asm volatile("s_waitcnt lgkmcnt(0)\ns_barrier" ::: "memory");
}

__device__ __forceinline__ void lgkm_wait() {
  asm volatile("s_waitcnt lgkmcnt(0)" ::: "memory");
}

// ---------------------------------------------------------------- prep: cast QKV->bf16, W->W^T bf16, rope tables
__global__ __launch_bounds__(256) void prep_kernel(
    const float* __restrict__ Qin, const float* __restrict__ Kin, const float* __restrict__ Vin,
    const float* __restrict__ Wq, const float* __restrict__ Wk,
    const float* __restrict__ Wv, const float* __restrict__ Wo,
    bf16* __restrict__ Qbf, bf16* __restrict__ Kbf, bf16* __restrict__ Vbf,
    bf16* __restrict__ WqT, bf16* __restrict__ WkT, bf16* __restrict__ WvT, bf16* __restrict__ WoT,
    bf16* __restrict__ cos_t, bf16* __restrict__ sin_t) {
  __shared__ float tile[64][65];
  int bx = blockIdx.x, t = threadIdx.x;
  if (bx < 3072) {
    int tz = bx >> 10, blk = bx & 1023;
    const float* src = tz == 0 ? Qin : tz == 1 ? Kin : Vin;
    bf16* dst = tz == 0 ? Qbf : tz == 1 ? Kbf : Vbf;
#pragma unroll
    for (int i = 0; i < 4; ++i) {
      int idx = blk * 1024 + i * 256 + t;  // float4 index
      float4 v = ((const float4*)src)[idx];
      union { bf16 b[4]; uint2 u; } tmp;
      tmp.b[0] = __float2bfloat16(v.x);
      tmp.b[1] = __float2bfloat16(v.y);
      tmp.b[2] = __float2bfloat16(v.z);
      tmp.b[3] = __float2bfloat16(v.w);
      ((uint2*)dst)[idx] = tmp.u;
    }
  } else if (bx < 4096) {
    int idx = bx - 3072;
    int z = idx >> 8;
    const float* W = z == 0 ? Wq : z == 1 ? Wk : z == 2 ? Wv : Wo;
    bf16* T = z == 0 ? WqT : z == 1 ? WkT : z == 2 ? WvT : WoT;
    int tk = (idx & 15) * 64, tn = ((idx >> 4) & 15) * 64;
    int c = t & 63, r0 = t >> 6;
#pragma unroll
    for (int i = 0; i < 16; ++i) {
      int r = i * 4 + r0;
      tile[r][c] = W[(size_t)(tk + r) * nD + tn + c];
    }
    __syncthreads();
#pragma unroll
    for (int i = 0; i < 16; ++i) {
      int r = i * 4 + r0;
      T[(size_t)(tn + r) * nD + tk + c] = __float2bfloat16(tile[c][r]);
    }
  } else {
    int base = (bx - 4096) * 1024 + t * 4;
#pragma unroll
    for (int i = 0; i < 4; ++i) {
      int e = base + i;
      int s = e >> 5, j = e & 31;
      float inv_freq = powf(100000.0f, -(float)(2 * j) / 64.0f);
      float g = (float)s * inv_freq;
      cos_t[e] = __float2bfloat16(cosf(g));
      sin_t[e] = __float2bfloat16(sinf(g));
    }
  }
}

// ---------------------------------------------------------------- fused projection GEMM v2: 128x128 tile, BK=32,
// 4 waves (2Mx2N, each 64x64), double-buffered 32 KiB LDS, 3-phase interleave with counted vmcnt.
// Grid 768 flattened (bijective XCD swizzle) = 3 blocks/CU -> barrier stalls overlap across blocks.
// LDS layout: paired rows — LDS row R (128 B, 8 chunks) holds global rows {2R,2R+1} x 32 k;
// chunk c_orig = (m&1)*4 + kchunk, stored at c_orig ^ (R&7).
// Per K-step T (cu = T&1):
//   p0: stage B(T+1)->buf^1 | 8 ds_read (all frags) | 8 MFMA (mi 0-1) | bar
//   p1: lgkmcnt(0) (cu reads drained)               | 4 MFMA (mi 2)   | bar
//   p2: stage A(T+2)->cu (safe after p1 bar)        | 4 MFMA (mi 3)   | vmcnt(2) | bar
__global__ __launch_bounds__(256, 3) void gemm_qkv_kernel(
    const bf16* __restrict__ A0, const bf16* __restrict__ A1, const bf16* __restrict__ A2,
    const bf16* __restrict__ Bt0, const bf16* __restrict__ Bt1, const bf16* __restrict__ Bt2,
    bf16* __restrict__ q_h, bf16* __restrict__ k_h, bf16* __restrict__ vt_h,
    const bf16* __restrict__ cos_t, const bf16* __restrict__ sin_t) {
  // flattened grid 768 = 3 z * 8 n * 32 m ; bijective XCD swizzle (768 % 8 == 0)
  const int bid = blockIdx.x;
  const int swz = (bid & 7) * 96 + (bid >> 3);
  const int z = swz >> 8;            // 0..2
  const int rem = swz & 255;
  const int n0 = (rem >> 5) * 128;   // 8 n-tiles
  const int m0 = (rem & 31) * 128;   // 32 m-tiles

  const bf16* __restrict__ A  = z == 0 ? A0 : (z == 1 ? A1 : A2);
  const bf16* __restrict__ Bt = z == 0 ? Bt0 : (z == 1 ? Bt1 : Bt2);

  __shared__ bf16 As[2 * 128 * 32];   // 16 KiB (two 8 KiB buffers)
  __shared__ bf16 Bs[2 * 128 * 32];   // 16 KiB

  const int t = threadIdx.x;          // 0..255
  const int lane = t & 63;
  const int wid = t >> 6;             // 0..3
  const int quad = lane >> 4;
  const int l16 = lane & 15;
  const int wm = wid >> 1;            // 0..1 -> 64 rows each
  const int wn = wid & 1;             // 0..1 -> 64 cols each (one head per wave)

  // staging constants: linear LDS dest (wave-uniform base + lane*16B), pre-swizzled global source
  const int sc    = (t & 7) ^ ((t >> 3) & 7);   // c_orig for this lane's 16B chunk
  const int sml   = 2 * (t >> 3) + (sc >> 2);   // m row 0..63 (first issue); +64 second
  const int skoff = (sc & 3) * 8;               // k element offset
  const int swave = wid * 512;                  // wave-uniform LDS elem base (first issue)

  // fragment-read constants
  const int R0a = wm * 32 + (l16 >> 1);
  const int R0b = wn * 32 + (l16 >> 1);
  const int cpar = (l16 & 1) * 4;
  const int abase = R0a * 64 + (((cpar + quad) ^ (R0a & 7)) * 8);  // + mi*512 (+buf)
  const int bbase = R0b * 64 + (((cpar + quad) ^ (R0b & 7)) * 8);  // + ni*512 (+buf)

#define STAGE_A(KT, BUF) do { \
    const bf16* ag_ = A + (size_t)(m0 + sml) * nD + (KT) * 32 + skoff; \
    gload_lds16(ag_, As + (BUF) + swave); \
    gload_lds16(ag_ + (size_t)64 * nD, As + (BUF) + 2048 + swave); \
  } while (0)
#define STAGE_B(KT, BUF) do { \
    const bf16* bg_ = Bt + (size_t)(n0 + sml) * nD + (KT) * 32 + skoff; \
    gload_lds16(bg_, Bs + (BUF) + swave); \
    gload_lds16(bg_ + (size_t)64 * nD, Bs + (BUF) + 2048 + swave); \
  } while (0)

  float4v acc[4][4] = {};

  // prologue: A(0),B(0) -> buf0; A(1) -> buf1; vmcnt(2) leaves A(1) in flight
  STAGE_A(0, 0);
  STAGE_B(0, 0);
  STAGE_A(1, 4096);
  asm volatile("s_waitcnt vmcnt(2)" ::: "memory");
  __builtin_amdgcn_s_barrier();

#pragma unroll 2
  for (int T = 0; T < 32; ++T) {
    const int cu = (T & 1) * 4096;
    const int nx = cu ^ 4096;

    // ---- phase 0: stage B(T+1) into other buf (drained at (T-1)p1); read all frags; mi 0-1
    if (T < 31) STAGE_B(T + 1, nx);
    Frag16B fa[4], fb[4];
#pragma unroll
    for (int mi = 0; mi < 4; ++mi) fa[mi].u4 = *(const uint4*)&As[cu + abase + mi * 512];
#pragma unroll
    for (int ni = 0; ni < 4; ++ni) fb[ni].u4 = *(const uint4*)&Bs[cu + bbase + ni * 512];
    __builtin_amdgcn_s_setprio(1);
#pragma unroll
    for (int mi = 0; mi < 2; ++mi)
#pragma unroll
      for (int ni = 0; ni < 4; ++ni)
        acc[mi][ni] = __builtin_amdgcn_mfma_f32_16x16x32_bf16(fa[mi].v, fb[ni].v, acc[mi][ni], 0, 0, 0);
    __builtin_amdgcn_s_setprio(0);
    __builtin_amdgcn_s_barrier();

    // ---- phase 1: drain own LDS reads; barrier => every wave done reading cu
    asm volatile("s_waitcnt lgkmcnt(0)" ::: "memory");
    __builtin_amdgcn_s_setprio(1);
#pragma unroll
    for (int ni = 0; ni < 4; ++ni)
      acc[2][ni] = __builtin_amdgcn_mfma_f32_16x16x32_bf16(fa[2].v, fb[ni].v, acc[2][ni], 0, 0, 0);
    __builtin_amdgcn_s_setprio(0);
    __builtin_amdgcn_s_barrier();

    // ---- phase 2: stage A(T+2) into cu (drained); counted vmcnt
    if (T < 30) STAGE_A(T + 2, cu);
    __builtin_amdgcn_s_setprio(1);
#pragma unroll
    for (int ni = 0; ni < 4; ++ni)
      acc[3][ni] = __builtin_amdgcn_mfma_f32_16x16x32_bf16(fa[3].v, fb[ni].v, acc[3][ni], 0, 0, 0);
    __builtin_amdgcn_s_setprio(0);
    if (T < 30) { asm volatile("s_waitcnt vmcnt(2)" ::: "memory"); }
    else        { asm volatile("s_waitcnt vmcnt(0)" ::: "memory"); }
    __builtin_amdgcn_s_barrier();
  }
#undef STAGE_A
#undef STAGE_B

  // ---- epilogue: RoPE + RMSNorm (q,k) or transposed store (v)
  const int col0 = n0 + wn * 64;   // multiple of 64 -> one head per wave
  if (z <= 1) {
    bf16* dst = z ? k_h : q_h;
#pragma unroll
    for (int mi = 0; mi < 4; ++mi)
#pragma unroll
      for (int r = 0; r < 4; ++r) {
        int row = m0 + wm * 64 + mi * 16 + quad * 4 + r;
        int s = row & (nS - 1);
        float x0 = acc[mi][0][r], x1 = acc[mi][1][r], x2 = acc[mi][2][r], x3 = acc[mi][3][r];
        float y[4];
#pragma unroll
        for (int p = 0; p < 2; ++p) {
          int d = p * 16 + l16;
          float c = __bfloat162float(cos_t[s * 32 + d]);
          float sn = __bfloat162float(sin_t[s * 32 + d]);
          float xa = p ? x1 : x0, xb = p ? x3 : x2;
          y[p] = xa * c + xb * sn;
          y[p + 2] = xb * c - xa * sn;
        }
        float ss = y[0] * y[0] + y[1] * y[1] + y[2] * y[2] + y[3] * y[3];
#pragma unroll
        for (int m = 1; m <= 8; m <<= 1) ss += __shfl_xor(ss, m, 64);
        float inv = 1.0f / sqrtf(ss * (1.0f / 64.0f) + 1e-9f);
#pragma unroll
        for (int ni = 0; ni < 4; ++ni)
          dst[(size_t)row * nD + col0 + ni * 16 + l16] = __float2bfloat16(y[ni] * inv);
      }
  } else {
    // V: write transposed -> vt_h [b][h][d][s]
#pragma unroll
    for (int mi = 0; mi < 4; ++mi)
#pragma unroll
      for (int r = 0; r < 4; ++r) {
        int row = m0 + wm * 64 + mi * 16 + quad * 4 + r;
        int b = row >> 11, s = row & (nS - 1);
#pragma unroll
        for (int ni = 0; ni < 4; ++ni) {
          int col = col0 + ni * 16 + l16;
          int h = col >> 6, d = col & 63;
          vt_h[((size_t)((b * nH + h) * 64 + d)) * nS + s] = __float2bfloat16(acc[mi][ni][r]);
        }
      }
  }
}

// ---------------------------------------------------------------- output GEMM: 64x128 tile, BK=64, grid (64, 8)
__global__ __launch_bounds__(256) void gemm_out_kernel(
    const bf16* __restrict__ A, const bf16* __restrict__ Bt, float* __restrict__ C) {
  __shared__ bf16 As[64 * 64];
  __shared__ bf16 Bs[128 * 64];
  const int t = threadIdx.x;
  const int lane = t & 63;
  const int wid = t >> 6;
  const int quad = lane >> 4;
  const int l16 = lane & 15;
  const int wm = wid >> 1;
  const int wn = wid & 1;
  const int m0 = blockIdx.x * 64;
  const int n0 = blockIdx.y * 128;
  const int K = nD;
  const int rloc = lane >> 3, cl = lane & 7;
  const int cg = cl ^ rloc;

  float4v acc[2][4] = {};
  for (int kt = 0; kt < K; kt += 64) {
    __syncthreads();
#pragma unroll
    for (int p = 0; p < 2; ++p) {
      int rowbase = (p * 4 + wid) * 8;
      gload_lds16(A + (size_t)(m0 + rowbase + rloc) * K + kt + cg * 8, As + (size_t)rowbase * 64);
    }
#pragma unroll
    for (int p = 0; p < 4; ++p) {
      int rowbase = (p * 4 + wid) * 8;
      gload_lds16(Bt + (size_t)(n0 + rowbase + rloc) * K + kt + cg * 8, Bs + (size_t)rowbase * 64);
    }
    __syncthreads();

#pragma unroll
    for (int ks = 0; ks < 2; ++ks) {
      Frag16B a[2], b[4];
#pragma unroll
      for (int mi = 0; mi < 2; ++mi) {
        int row = wm * 32 + mi * 16 + l16;
        int ch = (ks * 4 + quad) ^ (row & 7);
        a[mi].u4 = *(const uint4*)&As[row * 64 + ch * 8];
      }
#pragma unroll
      for (int ni = 0; ni < 4; ++ni) {
        int row = wn * 64 + ni * 16 + l16;
        int ch = (ks * 4 + quad) ^ (row & 7);
        b[ni].u4 = *(const uint4*)&Bs[row * 64 + ch * 8];
      }
#pragma unroll
      for (int mi = 0; mi < 2; ++mi)
#pragma unroll
        for (int ni = 0; ni < 4; ++ni)
          acc[mi][ni] = __builtin_amdgcn_mfma_f32_16x16x32_bf16(a[mi].v, b[ni].v, acc[mi][ni], 0, 0, 0);
    }
  }
#pragma unroll
  for (int mi = 0; mi < 2; ++mi)
#pragma unroll
    for (int ni = 0; ni < 4; ++ni)
#pragma unroll
      for (int r = 0; r < 4; ++r) {
        int row = m0 + wm * 32 + mi * 16 + quad * 4 + r;
        int col = n0 + wn * 64 + ni * 16 + l16;
        C[(size_t)row * nD + col] = acc[mi][ni][r];
      }
}

// ---------------------------------------------------------------- flash attention v8: KVBLK=128, 8-wave blocks,
// wave owns 16 q-rows. Main loop = full unmasked 128-key tiles (branchless); final diagonal tile
// handles all masking. K/V via global_load_lds, double-buffered 64 KiB LDS (2 blocks/CU),
// one vmcnt(0)+lgkm(0)+barrier per 128 keys.
static constexpr float SC = 0.18033688011112042f;  // 0.125 * log2(e)

__global__ __launch_bounds__(512, 4) void attn_kernel(const bf16* __restrict__ q_h,
                                                      const bf16* __restrict__ k_h,
                                                      const bf16* __restrict__ vt_h,
                                                      bf16* __restrict__ vals) {
  __shared__ bf16 lds_buf[4 * 8192];   // [K0|K1|V0|V1], 8192 elems each: K=128x64, V=2 half-subtiles 64x64

  const int t = threadIdx.x;           // 0..511
  const int lane = t & 63, wid = t >> 6, quad = lane >> 4, l16 = lane & 15;
  const int id = blockIdx.x;           // 0..511
  const int xcd = id & 7;              // round-robin XCD heuristic
  const int j = id >> 3;               // 0..63 per-XCD index
  const int jj = j & 31;
  const int bh = xcd * 4 + (jj & 3);   // 4 heads per XCD; pair blocks share bh
  const int u = jj >> 2;               // 0..7
  const int qt = (j < 32) ? (15 - u) : u;   // first CU-slot: long tiles; second: complementary short
  const int b = bh >> 4, h = bh & 15;

  const bf16* Kbase = k_h + ((size_t)b * nS) * nD + h * 64;
  const bf16* Vbase = vt_h + (size_t)bh * 64 * nS;  // [d][s]

  const int rl = lane >> 3;               // 0..7
  const int cg8 = ((lane & 7) ^ rl) * 8;  // pre-swizzled source chunk (elem offset)
  const int r7 = l16 & 7;

  bf16* const scratch = lds_buf + wid * 1152;  // 16 x 72 per wave (epilogue only)

  const int q0w = qt * 128 + wid * 16;         // wave's first q row

  // Q B-frags (col=q=l16, k=d), 2 d-halves
  Frag16B qf[2];
  {
    const bf16* qp = q_h + ((size_t)(b * nS + q0w + l16)) * nD + h * 64;
    qf[0].u4 = *(const uint4*)(qp + quad * 8);
    qf[1].u4 = *(const uint4*)(qp + 32 + quad * 8);
  }

  // stage 128-key K/V tile KT into buffer (KT&1): linear LDS dest, swizzled global source
#define STAGE_KV(KT) do { \
    const int bo_ = ((KT) & 1) * 8192; \
    const bf16* kg_ = Kbase + (size_t)((KT) * 128 + wid * 16 + rl) * nD + cg8; \
    gload_lds16(kg_, lds_buf + bo_ + wid * 1024); \
    gload_lds16(kg_ + (size_t)8 * nD, lds_buf + bo_ + wid * 1024 + 512); \
    const bf16* vg_ = Vbase + (size_t)(wid * 8 + rl) * nS + (KT) * 128 + cg8; \
    gload_lds16(vg_, lds_buf + 16384 + bo_ + wid * 512); \
    gload_lds16(vg_ + 64, lds_buf + 16384 + bo_ + 4096 + wid * 512); \
  } while (0)

  // QK^T for half HB of current K tile -> ST (S^T frags, key=row)
#define QKH(Kb, HB, ST) do { \
    _Pragma("unroll") \
    for (int kt4 = 0; kt4 < 4; ++kt4) { \
      int row = (HB) * 64 + kt4 * 16 + l16; \
      Frag16B k0_, k1_; \
      k0_.u4 = *(const uint4*)&(Kb)[row * 64 + ((quad ^ r7) * 8)]; \
      k1_.u4 = *(const uint4*)&(Kb)[row * 64 + (((quad + 4) ^ r7) * 8)]; \
      float4v zz_ = {}; \
      zz_ = __builtin_amdgcn_mfma_f32_16x16x32_bf16(k0_.v, qf[0].v, zz_, 0, 0, 0); \
      (ST)[kt4] = __builtin_amdgcn_mfma_f32_16x16x32_bf16(k1_.v, qf[1].v, zz_, 0, 0, 0); \
    } \
  } while (0)

  // exp (unmasked) ST -> PF, accumulate l_acc
#define EXPH(ST, PF) do { \
    _Pragma("unroll") \
    for (int kt4 = 0; kt4 < 4; ++kt4) \
      _Pragma("unroll") \
      for (int r = 0; r < 4; ++r) { \
        float p_ = fast_exp2((ST)[kt4][r] * SC); \
        l_acc += p_; \
        union { bf16 hh; short ss; } cv_; \
        cv_.hh = __float2bfloat16(p_); \
        (PF)[kt4][r] = cv_.ss; \
      } \
  } while (0)

  // exp (masked, diagonal tile) for half HB
#define EXPHM(ST, PF, HB) do { \
    int qg_ = q0w + l16; \
    _Pragma("unroll") \
    for (int kt4 = 0; kt4 < 4; ++kt4) { \
      int key0_ = qt * 128 + (HB) * 64 + kt4 * 16 + quad * 4; \
      _Pragma("unroll") \
      for (int r = 0; r < 4; ++r) { \
        float x_ = (ST)[kt4][r] * SC; \
        if (key0_ + r > qg_) x_ = -12000.0f; \
        float p_ = fast_exp2(x_); \
        l_acc += p_; \
        union { bf16 hh; short ss; } cv_; \
        cv_.hh = __float2bfloat16(p_); \
        (PF)[kt4][r] = cv_.ss; \
      } \
    } \
  } while (0)

  // O^T += V^T(half HB) . P^T
#define PVH(Vb, HB, PF) do { \
    _Pragma("unroll") \
    for (int dt = 0; dt < 4; ++dt) { \
      int row = dt * 16 + l16; \
      _Pragma("unroll") \
      for (int kt4 = 0; kt4 < 4; ++kt4) { \
        int chunk_ = kt4 * 2 + (quad >> 1); \
        union { uint2 u; short4v s; } vv_; \
        vv_.u = *(const uint2*)&(Vb)[(HB) * 4096 + row * 64 + ((chunk_ ^ r7) * 8) + (quad & 1) * 4]; \
        o_acc[dt] = __builtin_amdgcn_mfma_f32_16x16x16bf16_1k(vv_.s, (PF)[kt4], o_acc[dt], 0, 0, 0); \
      } \
    } \
  } while (0)

  STAGE_KV(0);
  asm volatile("s_waitcnt vmcnt(0)" ::: "memory");
  __builtin_amdgcn_s_barrier();

  float4v o_acc[4] = {};
  float l_acc = 0.f;

  // ---- main loop: full unmasked tiles (branchless)
  for (int kt = 0; kt < qt; ++kt) {
    STAGE_KV(kt + 1);
    const bf16* Kb = lds_buf + (kt & 1) * 8192;
    const bf16* Vb = lds_buf + 16384 + (kt & 1) * 8192;

    float4v st0[4], st1[4];
    __builtin_amdgcn_s_setprio(1);
    QKH(Kb, 0, st0);
    QKH(Kb, 1, st1);
    __builtin_amdgcn_s_setprio(0);

    short4v pf[4];
    EXPH(st0, pf);
    __builtin_amdgcn_s_setprio(1);
    PVH(Vb, 0, pf);
    __builtin_amdgcn_s_setprio(0);
    EXPH(st1, pf);
    __builtin_amdgcn_s_setprio(1);
    PVH(Vb, 1, pf);
    __builtin_amdgcn_s_setprio(0);

    asm volatile("s_waitcnt vmcnt(0) lgkmcnt(0)" ::: "memory");
    __builtin_amdgcn_s_barrier();
  }

  // ---- final diagonal tile kt = qt (no prefetch; all masking lives here)
  {
    const bf16* Kb = lds_buf + (qt & 1) * 8192;
    const bf16* Vb = lds_buf + 16384 + (qt & 1) * 8192;

    float4v st0[4];
    QKH(Kb, 0, st0);
    short4v pf[4];
    EXPHM(st0, pf, 0);
    PVH(Vb, 0, pf);

    if (wid >= 4) {   // waves 0-3: h1 keys are all > q0w+15 (fully masked) -> skip
      float4v st1[4];
      QKH(Kb, 1, st1);
      EXPHM(st1, pf, 1);
      PVH(Vb, 1, pf);
    }
  }
#undef STAGE_KV
#undef QKH
#undef EXPH
#undef EXPHM
#undef PVH

  // all waves done reading K/V before scratch (overlapping K region) is overwritten
  lds_barrier();

  // ---- epilogue: row-sum reduce, LDS-transpose, coalesced 16B stores
  float la = l_acc;
  la += __shfl_xor(la, 16, 64);
  la += __shfl_xor(la, 32, 64);
  float inv_l = 1.0f / la;
  // write transposed: scratch[q_loc=l16][d]
#pragma unroll
  for (int dt = 0; dt < 4; ++dt) {
    union { bf16 b2[2]; uint u; } p01, p23;
    p01.b2[0] = __float2bfloat16(o_acc[dt][0] * inv_l);
    p01.b2[1] = __float2bfloat16(o_acc[dt][1] * inv_l);
    p23.b2[0] = __float2bfloat16(o_acc[dt][2] * inv_l);
    p23.b2[1] = __float2bfloat16(o_acc[dt][3] * inv_l);
    *(uint*)&scratch[l16 * 72 + dt * 16 + quad * 4] = p01.u;
    *(uint*)&scratch[l16 * 72 + dt * 16 + quad * 4 + 2] = p23.u;
  }
  lgkm_wait();  // own writes visible to own reads
  uint4 r0 = *(const uint4*)&scratch[l16 * 72 + quad * 16];
  uint4 r1 = *(const uint4*)&scratch[l16 * 72 + quad * 16 + 8];
  int qrow = q0w + l16;
  bf16* vp = vals + ((size_t)(b * nS + qrow)) * nD + h * 64 + quad * 16;
  *(uint4*)(vp) = r0;
  *(uint4*)(vp + 8) = r1;
}

// ---------------------------------------------------------------- launch
extern "C" void kernel_launch(void* const* d_in, const int* in_sizes, int n_in,
                              void* d_out, int out_size, void* d_ws, size_t ws_size,
                              hipStream_t stream) {
  const float* Qin = (const float*)d_in[0];
  const float* Kin = (const float*)d_in[1];
  const float* Vin = (const float*)d_in[2];
  const float* Wq = (const float*)d_in[4];
  const float* Wk = (const float*)d_in[5];
  const float* Wv = (const float*)d_in[6];
  const float* Wo = (const float*)d_in[7];
  float* out = (float*)d_out;

  char* ws = (char*)d_ws;
  const size_t MB = 1u << 20;
  bf16* Qbf = (bf16*)(ws + 0 * MB);
  bf16* Kbf = (bf16*)(ws + 8 * MB);
  bf16* Vbf = (bf16*)(ws + 16 * MB);
  bf16* WqT = (bf16*)(ws + 24 * MB);
  bf16* WkT = (bf16*)(ws + 26 * MB);
  bf16* WvT = (bf16*)(ws + 28 * MB);
  bf16* WoT = (bf16*)(ws + 30 * MB);
  bf16* cos_t = (bf16*)(ws + 32 * MB);
  bf16* sin_t = (bf16*)(ws + 33 * MB);
  bf16* q_h = (bf16*)(ws + 34 * MB);
  bf16* k_h = (bf16*)(ws + 42 * MB);
  bf16* vt_h = (bf16*)(ws + 50 * MB);
  bf16* vals = (bf16*)(ws + 58 * MB);

  prep_kernel<<<4160, 256, 0, stream>>>(Qin, Kin, Vin, Wq, Wk, Wv, Wo,
                                        Qbf, Kbf, Vbf, WqT, WkT, WvT, WoT, cos_t, sin_t);

  gemm_qkv_kernel<<<768, 256, 0, stream>>>(Qbf, Kbf, Vbf, WqT, WkT, WvT,
                                           q_h, k_h, vt_h, cos_t, sin_t);

  attn_kernel<<<512, 512, 0, stream>>>(q_h, k_h, vt_h, vals);

  gemm_out_kernel<<<dim3(64, 8), 256, 0, stream>>>(vals, WoT, out);
}